// Round 6
// baseline (428.198 us; speedup 1.0000x reference)
//
#include <hip/hip_runtime.h>
#include <hip/hip_bf16.h>
#include <hip/hip_cooperative_groups.h>
#include <math.h>

namespace cg = cooperative_groups;

#define D 64
#define H 4
#define NB 4
#define TILE 64
#define MAXDEG 256
#define NEG_SLOPE 0.2f

typedef __attribute__((ext_vector_type(8))) short short8;
typedef __attribute__((ext_vector_type(4))) float f32x4;

__device__ __forceinline__ unsigned short f2bf(float f) {
    union { float f; unsigned int u; } c; c.f = f;
    const unsigned int u = c.u;
    return (unsigned short)((u + 0x7fffu + ((u >> 16) & 1u)) >> 16);
}

// ======================= MEGA (cooperative) =======================
struct MegaParams {
    const float *emb, *Qw, *Qb, *Kw, *Kb, *Vw, *Vb, *W0, *b0, *W1, *b1, *W2, *b2, *Pw, *Pb;
    const int *src, *dst, *bond;
    unsigned short *Qbf, *Kbf, *W0p, *W1p;
    float *V, *scores, *out;
    int *rowStart, *bondOff, *edge_col, *edge_eid, *bond_edges;
    int *blockBondCnt, *blockBondBase, *counters, *tileBt, *tileT0, *ntiles;
    int N, Ep, TE, nblk, nq;
};

struct SMemMlp {
    unsigned char xs[64 * 256];        // 16 KB, XOR-swizzled X tile
    unsigned char h0s[4][64 * 128];    // 32 KB, per-wave H0
    int eids[64];
};
struct SMemAgg {
    int tcol[MAXDEG], teid[MAXDEG], scol[MAXDEG], seid[MAXDEG], win[MAXDEG];
    float wgt[4][MAXDEG];
    float r[256];
    float part2[4][64];
};
struct SMemScan { int part[256]; int tpre[8]; };
struct SMemQkv  { float e[4][64]; };
struct SMemCnt  { int wcnt[4][NB]; int wbase[4][NB]; };
union SMemU {
    SMemMlp mlp; SMemAgg agg; SMemScan scan; SMemQkv qkv; SMemCnt cnt;
};

__global__ __launch_bounds__(256, 2) void mega_kernel(MegaParams P)
{
    __shared__ __align__(16) SMemU sm;
    cg::grid_group grid = cg::this_grid();
    const int tid = threadIdx.x;
    const int bid = blockIdx.x;
    const int grd = gridDim.x;
    const int lane = tid & 63, wave = tid >> 6;
    int* rowCnt  = P.counters;
    int* rowFill = P.counters + P.N;

    // ---------- P0: zero counters + QKV + weight prepack ----------
    for (int i = bid * 256 + tid; i < 2 * P.N; i += grd * 256) P.counters[i] = 0;

    for (int vb = bid; vb < P.nq; vb += grd) {
        __syncthreads();
        const int n = vb * 4 + wave, d = lane;
        if (n < P.N) sm.qkv.e[wave][d] = P.emb[n * D + d];
        __syncthreads();
        if (n < P.N) {
            float aq = P.Qb[d], ak = P.Kb[d], av = P.Vb[d];
            const float* er = sm.qkv.e[wave];
#pragma unroll 8
            for (int k = 0; k < D; ++k) {
                const float x = er[k];
                aq += x * P.Qw[k * D + d];
                ak += x * P.Kw[k * D + d];
                av += x * P.Vw[k * D + d];
            }
            P.Qbf[n * D + d] = f2bf(aq);
            P.Kbf[n * D + d] = f2bf(ak);
            P.V[n * D + d] = av;
        }
    }
    for (int vb = bid; vb < 512; vb += grd) {
        const int idx = vb * 256 + tid;   // < 131072
        {
            const int j = idx & 7, ln = (idx >> 3) & 63, nt = (idx >> 9) & 3;
            const int ks = (idx >> 11) & 3, bh = idx >> 13;
            const int k = ks * 32 + ((ln >> 4) << 3) + j;
            const int nn = (nt << 4) + (ln & 15);
            P.W0p[idx] = f2bf(P.W0[((size_t)bh * 128 + k) * 64 + nn]);
        }
        if (idx < 65536) {
            const int j = idx & 7, ln = (idx >> 3) & 63, nt = (idx >> 9) & 3;
            const int ks = (idx >> 11) & 1, bh = idx >> 12;
            const int k = ks * 32 + ((ln >> 4) << 3) + j;
            const int nn = (nt << 4) + (ln & 15);
            P.W1p[idx] = f2bf(P.W1[((size_t)bh * 64 + k) * 64 + nn]);
        }
    }
    grid.sync();

    // ---------- P1: count (row atomics + per-vblock bond histogram) ----------
    for (int vb = bid; vb < P.nblk; vb += grd) {
        __syncthreads();
        const int e = vb * 256 + tid;
        const bool act = (e < P.TE);
        int bt = -1;
        if (act) {
            const int s = (e < P.Ep) ? P.src[e] : P.dst[e - P.Ep];
            bt = (e < P.Ep) ? P.bond[e] : P.bond[e - P.Ep];
            atomicAdd(&rowCnt[s], 1);
        }
#pragma unroll
        for (int t = 0; t < NB; ++t) {
            const unsigned long long m = __ballot(bt == t);
            if (lane == 0) sm.cnt.wcnt[wave][t] = (int)__popcll(m);
        }
        __syncthreads();
        if (tid < NB) {
            int s = 0;
#pragma unroll
            for (int w = 0; w < 4; ++w) s += sm.cnt.wcnt[w][tid];
            P.blockBondCnt[tid * P.nblk + vb] = s;
        }
    }
    grid.sync();

    // ---------- P2: scans + tile list (block 0 only) ----------
    if (bid == 0) {
        const int t = tid;
        // phase 1: rowStart
        {
            const int b0i = t * 16;
            int s = 0;
            for (int i = 0; i < 16; ++i) { const int idx = b0i + i; if (idx < P.N) s += rowCnt[idx]; }
            sm.scan.part[t] = s;
            __syncthreads();
            int val = s;
            for (int off = 1; off < 256; off <<= 1) {
                const int o = (t >= off) ? sm.scan.part[t - off] : 0;
                __syncthreads();
                val += o;
                sm.scan.part[t] = val;
                __syncthreads();
            }
            int run = val - s;
            for (int i = 0; i < 16; ++i) {
                const int idx = b0i + i;
                if (idx < P.N) { P.rowStart[idx] = run; run += rowCnt[idx]; }
            }
            if (t == 255) P.rowStart[P.N] = val;
            __syncthreads();
        }
        // phase 2: blockBondBase + bondOff + tile list
        {
            const int M = NB * P.nblk;
            const int c = (M + 255) >> 8;
            const int b2i = t * c;
            int s = 0;
            for (int i = 0; i < c; ++i) { const int idx = b2i + i; if (idx < M) s += P.blockBondCnt[idx]; }
            sm.scan.part[t] = s;
            __syncthreads();
            int val = s;
            for (int off = 1; off < 256; off <<= 1) {
                const int o = (t >= off) ? sm.scan.part[t - off] : 0;
                __syncthreads();
                val += o;
                sm.scan.part[t] = val;
                __syncthreads();
            }
            int run = val - s;
            for (int i = 0; i < c; ++i) {
                const int idx = b2i + i;
                if (idx < M) { P.blockBondBase[idx] = run; run += P.blockBondCnt[idx]; }
            }
            __syncthreads();
            if (t < NB) P.bondOff[t] = P.blockBondBase[t * P.nblk];
            if (t == 0) P.bondOff[NB] = sm.scan.part[255];
            __syncthreads();
            if (t == 0) {
                sm.scan.tpre[0] = 0;
                for (int b = 0; b < NB; ++b) {
                    const int cnt = P.bondOff[b + 1] - P.bondOff[b];
                    sm.scan.tpre[b + 1] = sm.scan.tpre[b] + ((cnt + 63) >> 6);
                }
                P.ntiles[0] = sm.scan.tpre[NB];
            }
            __syncthreads();
            for (int i = t; i < sm.scan.tpre[NB]; i += 256) {
                int b = 0;
                while (i >= sm.scan.tpre[b + 1]) ++b;
                P.tileBt[i] = b;
                P.tileT0[i] = (i - sm.scan.tpre[b]) << 6;
            }
        }
    }
    grid.sync();

    // ---------- P3: scatter ----------
    for (int vb = bid; vb < P.nblk; vb += grd) {
        __syncthreads();
        const int e = vb * 256 + tid;
        const bool act = (e < P.TE);
        int s = 0, d = 0, bt = -1;
        if (act) {
            if (e < P.Ep) { s = P.src[e]; d = P.dst[e]; bt = P.bond[e]; }
            else          { s = P.dst[e - P.Ep]; d = P.src[e - P.Ep]; bt = P.bond[e - P.Ep]; }
            const int p = P.rowStart[s] + atomicAdd(&rowFill[s], 1);
            P.edge_col[p] = d;
            P.edge_eid[p] = e;
        }
        int myrank = 0;
#pragma unroll
        for (int t = 0; t < NB; ++t) {
            const unsigned long long m = __ballot(bt == t);
            if (lane == 0) sm.cnt.wcnt[wave][t] = (int)__popcll(m);
            if (bt == t) myrank = (int)__popcll(m & ((1ull << lane) - 1ull));
        }
        __syncthreads();
        if (tid < NB) {
            int sum = 0;
#pragma unroll
            for (int w = 0; w < 4; ++w) { sm.cnt.wbase[w][tid] = sum; sum += sm.cnt.wcnt[w][tid]; }
        }
        __syncthreads();
        if (act) {
            const int q = P.blockBondBase[bt * P.nblk + vb] + sm.cnt.wbase[wave][bt] + myrank;
            P.bond_edges[q] = e;
        }
    }
    grid.sync();

    // ---------- P4: MFMA grouped edge MLP over exact tile list ----------
    const int ntt = P.ntiles[0];
    const int lg = lane >> 4;
    const int lr = lane & 15;
    for (int vt = bid; vt < ntt; vt += grd) {
        __syncthreads();
        const int bt = P.tileBt[vt];
        const int t0 = P.tileT0[vt];
        const int base = P.bondOff[bt];
        const int cnt = P.bondOff[bt + 1] - base;
        const int ne = min(TILE, cnt - t0);

        if (tid < TILE) sm.mlp.eids[tid] = (tid < ne) ? P.bond_edges[base + t0 + tid] : 0;
        __syncthreads();

        for (int i = tid; i < 1024; i += 256) {
            const int el = i >> 4, u = i & 15;
            uint4 v = make_uint4(0, 0, 0, 0);
            if (el < ne) {
                const int e = sm.mlp.eids[el];
                int s, d;
                if (e < P.Ep) { s = P.src[e]; d = P.dst[e]; }
                else          { s = P.dst[e - P.Ep]; d = P.src[e - P.Ep]; }
                v = (u < 8) ? ((const uint4*)(P.Qbf + s * 64))[u]
                            : ((const uint4*)(P.Kbf + d * 64))[u - 8];
            }
            const int b = (el << 8) + (u << 4);
            *(uint4*)(sm.mlp.xs + (b ^ ((el & 7) << 4))) = v;
        }
        __syncthreads();

        const int h = wave;
        const int bh = bt * H + h;

        // layer 0
        f32x4 acc[4][4];
        const float* bb0 = P.b0 + bh * 64;
#pragma unroll
        for (int nt = 0; nt < 4; ++nt) {
            const float bv = bb0[(nt << 4) + lr];
#pragma unroll
            for (int mt = 0; mt < 4; ++mt) acc[mt][nt] = (f32x4){bv, bv, bv, bv};
        }
        const short8* W0f = (const short8*)P.W0p + (size_t)bh * 1024;
#pragma unroll
        for (int ks = 0; ks < 4; ++ks) {
            short8 a[4];
            const int koff = (ks << 6) + (lg << 4);
#pragma unroll
            for (int mt = 0; mt < 4; ++mt) {
                const int row = (mt << 4) + lr;
                const int b = (row << 8) + koff;
                a[mt] = *(const short8*)(sm.mlp.xs + (b ^ ((row & 7) << 4)));
            }
            short8 bfr[4];
#pragma unroll
            for (int nt = 0; nt < 4; ++nt) bfr[nt] = W0f[(((ks << 2) + nt) << 6) + lane];
#pragma unroll
            for (int mt = 0; mt < 4; ++mt)
#pragma unroll
                for (int nt = 0; nt < 4; ++nt)
                    acc[mt][nt] = __builtin_amdgcn_mfma_f32_16x16x32_bf16(a[mt], bfr[nt], acc[mt][nt], 0, 0, 0);
        }
        unsigned char* h0 = sm.mlp.h0s[h];
#pragma unroll
        for (int mt = 0; mt < 4; ++mt)
#pragma unroll
            for (int nt = 0; nt < 4; ++nt)
#pragma unroll
                for (int r = 0; r < 4; ++r) {
                    const int row = (mt << 4) + (lg << 2) + r;
                    const int col = (nt << 4) + lr;
                    const int b = (row << 7) + (col << 1);
                    *(unsigned short*)(h0 + (b ^ ((row & 7) << 4))) = f2bf(fmaxf(acc[mt][nt][r], 0.f));
                }

        // layer 1
        f32x4 acc1[4][4];
        const float* bb1 = P.b1 + bh * 64;
#pragma unroll
        for (int nt = 0; nt < 4; ++nt) {
            const float bv = bb1[(nt << 4) + lr];
#pragma unroll
            for (int mt = 0; mt < 4; ++mt) acc1[mt][nt] = (f32x4){bv, bv, bv, bv};
        }
        const short8* W1f = (const short8*)P.W1p + (size_t)bh * 512;
#pragma unroll
        for (int ks = 0; ks < 2; ++ks) {
            short8 a[4];
            const int koff = (ks << 6) + (lg << 4);
#pragma unroll
            for (int mt = 0; mt < 4; ++mt) {
                const int row = (mt << 4) + lr;
                const int b = (row << 7) + koff;
                a[mt] = *(const short8*)(h0 + (b ^ ((row & 7) << 4)));
            }
            short8 bfr[4];
#pragma unroll
            for (int nt = 0; nt < 4; ++nt) bfr[nt] = W1f[(((ks << 2) + nt) << 6) + lane];
#pragma unroll
            for (int mt = 0; mt < 4; ++mt)
#pragma unroll
                for (int nt = 0; nt < 4; ++nt)
                    acc1[mt][nt] = __builtin_amdgcn_mfma_f32_16x16x32_bf16(a[mt], bfr[nt], acc1[mt][nt], 0, 0, 0);
        }

        // layer 2 + leaky relu
        const float* w2 = P.W2 + bh * 64;
        float w2v[4];
#pragma unroll
        for (int nt = 0; nt < 4; ++nt) w2v[nt] = w2[(nt << 4) + lr];
        float p[4][4];
#pragma unroll
        for (int mt = 0; mt < 4; ++mt)
#pragma unroll
            for (int r = 0; r < 4; ++r) {
                float s = 0.f;
#pragma unroll
                for (int nt = 0; nt < 4; ++nt) s += fmaxf(acc1[mt][nt][r], 0.f) * w2v[nt];
                p[mt][r] = s;
            }
#pragma unroll
        for (int off = 1; off <= 8; off <<= 1)
#pragma unroll
            for (int mt = 0; mt < 4; ++mt)
#pragma unroll
                for (int r = 0; r < 4; ++r) p[mt][r] += __shfl_xor(p[mt][r], off, 64);
        const int e_w = ((lr >> 2) << 4) + (lg << 2) + (lr & 3);
        float sc = p[lr >> 2][lr & 3] + P.b2[bh];
        sc = sc > 0.f ? sc : NEG_SLOPE * sc;
        if (e_w < ne) P.scores[(size_t)sm.mlp.eids[e_w] * H + h] = sc;
    }
    grid.sync();

    // ---------- P5: softmax + V-aggregate + fused projection ----------
    for (int row = bid; row < P.N; row += grd) {
        __syncthreads();
        const int beg = P.rowStart[row];
        int deg = P.rowStart[row + 1] - beg;
        if (deg > MAXDEG) deg = MAXDEG;

        for (int a = tid; a < deg; a += 256) {
            sm.agg.tcol[a] = P.edge_col[beg + a];
            sm.agg.teid[a] = P.edge_eid[beg + a];
        }
        __syncthreads();
        for (int a = tid; a < deg; a += 256) {
            const int e = sm.agg.teid[a];
            int r = 0;
            for (int b = 0; b < deg; ++b) r += (sm.agg.teid[b] < e);
            sm.agg.scol[r] = sm.agg.tcol[a];
            sm.agg.seid[r] = e;
        }
        __syncthreads();
        for (int a = tid; a < deg; a += 256) {
            const int c = sm.agg.scol[a];
            int wn = 1;
            for (int b = a + 1; b < deg; ++b) if (sm.agg.scol[b] == c) { wn = 0; break; }
            sm.agg.win[a] = wn;
        }
        __syncthreads();

        const int h = wave;
        float m = -1e30f;
        for (int a = lane; a < deg; a += 64)
            if (sm.agg.win[a]) m = fmaxf(m, P.scores[(size_t)sm.agg.seid[a] * H + h]);
#pragma unroll
        for (int off = 32; off; off >>= 1) m = fmaxf(m, __shfl_xor(m, off, 64));

        float dn = 0.f;
        for (int a = lane; a < deg; a += 64) {
            const float wv = sm.agg.win[a] ? __expf(P.scores[(size_t)sm.agg.seid[a] * H + h] - m) : 0.f;
            sm.agg.wgt[h][a] = wv;
            dn += wv;
        }
#pragma unroll
        for (int off = 32; off; off >>= 1) dn += __shfl_xor(dn, off, 64);

        float accv = 0.f;
        for (int a = 0; a < deg; ++a) {
            const float wv = sm.agg.wgt[h][a];
            if (wv != 0.f) accv += wv * P.V[(size_t)sm.agg.scol[a] * D + lane];
        }
        sm.agg.r[tid] = accv / dn;
        __syncthreads();

        {
            float s = 0.f;
#pragma unroll 8
            for (int k = 0; k < 64; ++k) s += sm.agg.r[wave * 64 + k] * P.Pw[(wave * 64 + k) * D + lane];
            sm.agg.part2[wave][lane] = s;
        }
        __syncthreads();
        if (tid < 64)
            P.out[(size_t)row * D + tid] = sm.agg.part2[0][tid] + sm.agg.part2[1][tid]
                                         + sm.agg.part2[2][tid] + sm.agg.part2[3][tid] + P.Pb[tid];
    }
}

// ======================= FALLBACK (round-5 proven path) =======================
__global__ __launch_bounds__(256) void prep_kernel(
    const float* __restrict__ emb,
    const float* __restrict__ Qw, const float* __restrict__ Qb,
    const float* __restrict__ Kw, const float* __restrict__ Kb,
    const float* __restrict__ Vw, const float* __restrict__ Vb,
    unsigned short* __restrict__ Qbf, unsigned short* __restrict__ Kbf,
    float* __restrict__ V,
    const float* __restrict__ W0, const float* __restrict__ W1,
    unsigned short* __restrict__ W0p, unsigned short* __restrict__ W1p,
    int* __restrict__ counters, int N, int nq)
{
    const int tid = threadIdx.x;
    if (blockIdx.x < nq) {
        const int gz = blockIdx.x * 256 + tid;
        if (gz < 2 * N) counters[gz] = 0;
        __shared__ float e[4][64];
        const int n = blockIdx.x * 4 + (tid >> 6);
        const int d = tid & 63;
        if (n < N) e[tid >> 6][d] = emb[n * D + d];
        __syncthreads();
        if (n < N) {
            float aq = Qb[d], ak = Kb[d], av = Vb[d];
            const float* er = e[tid >> 6];
#pragma unroll 8
            for (int k = 0; k < D; ++k) {
                const float x = er[k];
                aq += x * Qw[k * D + d];
                ak += x * Kw[k * D + d];
                av += x * Vw[k * D + d];
            }
            Qbf[n * D + d] = f2bf(aq);
            Kbf[n * D + d] = f2bf(ak);
            V[n * D + d] = av;
        }
    } else {
        const int idx = (blockIdx.x - nq) * 256 + tid;
        if (idx < 131072) {
            const int j = idx & 7, lane = (idx >> 3) & 63, nt = (idx >> 9) & 3;
            const int ks = (idx >> 11) & 3, bh = idx >> 13;
            const int k = ks * 32 + ((lane >> 4) << 3) + j;
            const int nn = (nt << 4) + (lane & 15);
            W0p[idx] = f2bf(W0[((size_t)bh * 128 + k) * 64 + nn]);
        }
        if (idx < 65536) {
            const int j = idx & 7, lane = (idx >> 3) & 63, nt = (idx >> 9) & 3;
            const int ks = (idx >> 11) & 1, bh = idx >> 12;
            const int k = ks * 32 + ((lane >> 4) << 3) + j;
            const int nn = (nt << 4) + (lane & 15);
            W1p[idx] = f2bf(W1[((size_t)bh * 64 + k) * 64 + nn]);
        }
    }
}

__global__ void count_kernel(const int* __restrict__ src, const int* __restrict__ dst,
                             const int* __restrict__ bond, int Ep,
                             int* __restrict__ rowCnt, int* __restrict__ blockBondCnt, int nblk)
{
    __shared__ int wcnt[4][NB];
    const int e = blockIdx.x * 256 + threadIdx.x;
    const int lane = threadIdx.x & 63;
    const int wave = threadIdx.x >> 6;
    const bool act = (e < 2 * Ep);
    int bt = -1;
    if (act) {
        const int s = (e < Ep) ? src[e] : dst[e - Ep];
        bt = (e < Ep) ? bond[e] : bond[e - Ep];
        atomicAdd(&rowCnt[s], 1);
    }
#pragma unroll
    for (int t = 0; t < NB; ++t) {
        const unsigned long long mask = __ballot(bt == t);
        if (lane == 0) wcnt[wave][t] = (int)__popcll(mask);
    }
    __syncthreads();
    if (threadIdx.x < NB) {
        int s = 0;
#pragma unroll
        for (int w = 0; w < 4; ++w) s += wcnt[w][threadIdx.x];
        blockBondCnt[threadIdx.x * nblk + blockIdx.x] = s;
    }
}

__global__ void scan_kernel(const int* __restrict__ rowCnt, int* __restrict__ rowStart,
                            const int* __restrict__ blockBondCnt, int* __restrict__ blockBondBase,
                            int* __restrict__ bondOff, int N, int nblk,
                            int* __restrict__ tileBt, int* __restrict__ tileT0, int* __restrict__ ntiles)
{
    __shared__ int part[1024];
    __shared__ int sbase[2048];
    __shared__ int tpre[NB + 1];
    const int t = threadIdx.x;
    {
        const int base = t * 4;
        int loc[4];
        int s = 0;
#pragma unroll
        for (int i = 0; i < 4; ++i) {
            const int idx = base + i;
            const int v = (idx < N) ? rowCnt[idx] : 0;
            loc[i] = s;
            s += v;
        }
        part[t] = s;
        __syncthreads();
        int val = s;
        for (int off = 1; off < 1024; off <<= 1) {
            const int other = (t >= off) ? part[t - off] : 0;
            __syncthreads();
            val += other;
            part[t] = val;
            __syncthreads();
        }
        const int excl = val - s;
#pragma unroll
        for (int i = 0; i < 4; ++i) {
            const int idx = base + i;
            if (idx < N) rowStart[idx] = excl + loc[i];
        }
        if (t == 1023) rowStart[N] = val;
    }
    __syncthreads();
    {
        const int M = NB * nblk;
        int loc[2];
        int s = 0;
#pragma unroll
        for (int i = 0; i < 2; ++i) {
            const int idx = t * 2 + i;
            const int v = (idx < M) ? blockBondCnt[idx] : 0;
            loc[i] = s;
            s += v;
        }
        part[t] = s;
        __syncthreads();
        int val = s;
        for (int off = 1; off < 1024; off <<= 1) {
            const int other = (t >= off) ? part[t - off] : 0;
            __syncthreads();
            val += other;
            part[t] = val;
            __syncthreads();
        }
        const int excl = val - s;
#pragma unroll
        for (int i = 0; i < 2; ++i) {
            const int idx = t * 2 + i;
            if (idx < M) sbase[idx] = excl + loc[i];
        }
        if (t == 1023) bondOff[NB] = val;
        __syncthreads();
#pragma unroll
        for (int i = 0; i < 2; ++i) {
            const int idx = t * 2 + i;
            if (idx < M) blockBondBase[idx] = sbase[idx];
        }
        if (t == 0) {
            bondOff[0] = 0;
            for (int b = 1; b < NB; ++b) bondOff[b] = sbase[b * nblk];
        }
        __syncthreads();
        if (t == 0) {
            tpre[0] = 0;
            const int total = bondOff[NB];
            for (int b = 0; b < NB; ++b) {
                const int lo = (b == 0) ? 0 : sbase[b * nblk];
                const int hi = (b == NB - 1) ? total : sbase[(b + 1) * nblk];
                tpre[b + 1] = tpre[b] + ((hi - lo + 63) >> 6);
            }
            ntiles[0] = tpre[NB];
        }
        __syncthreads();
        for (int i = t; i < tpre[NB]; i += 1024) {
            int b = 0;
            while (i >= tpre[b + 1]) ++b;
            tileBt[i] = b;
            tileT0[i] = (i - tpre[b]) << 6;
        }
    }
}

__global__ void scatter_kernel(const int* __restrict__ src, const int* __restrict__ dst,
                               const int* __restrict__ bond, int Ep,
                               const int* __restrict__ rowStart, int* __restrict__ rowFill,
                               const int* __restrict__ blockBondBase, int nblk,
                               int* __restrict__ edge_col, int* __restrict__ edge_eid,
                               int* __restrict__ bond_edges)
{
    __shared__ int wcnt[4][NB];
    __shared__ int wbase[4][NB];
    const int e = blockIdx.x * 256 + threadIdx.x;
    const int lane = threadIdx.x & 63;
    const int wave = threadIdx.x >> 6;
    const bool act = (e < 2 * Ep);
    int s = 0, d = 0, bt = -1;
    if (act) {
        if (e < Ep) { s = src[e]; d = dst[e]; bt = bond[e]; }
        else        { s = dst[e - Ep]; d = src[e - Ep]; bt = bond[e - Ep]; }
        const int p = rowStart[s] + atomicAdd(&rowFill[s], 1);
        edge_col[p] = d;
        edge_eid[p] = e;
    }
    int myrank = 0;
#pragma unroll
    for (int t = 0; t < NB; ++t) {
        const unsigned long long mask = __ballot(bt == t);
        if (lane == 0) wcnt[wave][t] = (int)__popcll(mask);
        if (bt == t) myrank = (int)__popcll(mask & ((1ull << lane) - 1ull));
    }
    __syncthreads();
    if (threadIdx.x < NB) {
        int sum = 0;
#pragma unroll
        for (int w = 0; w < 4; ++w) { wbase[w][threadIdx.x] = sum; sum += wcnt[w][threadIdx.x]; }
    }
    __syncthreads();
    if (act) {
        const int q = blockBondBase[bt * nblk + blockIdx.x] + wbase[wave][bt] + myrank;
        bond_edges[q] = e;
    }
}

__global__ __launch_bounds__(256) void mlp_kernel(
    const unsigned short* __restrict__ Qbf, const unsigned short* __restrict__ Kbf,
    const int* __restrict__ src, const int* __restrict__ dst, int Ep,
    const int* __restrict__ bondOff, const int* __restrict__ bond_edges,
    const unsigned short* __restrict__ W0p, const unsigned short* __restrict__ W1p,
    const float* __restrict__ b0, const float* __restrict__ b1,
    const float* __restrict__ W2, const float* __restrict__ b2,
    float* __restrict__ scores)
{
    const int bt = blockIdx.y;
    const int base = bondOff[bt];
    const int cnt  = bondOff[bt + 1] - base;
    const int t0 = blockIdx.x * TILE;
    if (t0 >= cnt) return;
    const int ne = min(TILE, cnt - t0);

    __shared__ __align__(16) unsigned char xs[64 * 256];
    __shared__ __align__(16) unsigned char h0s[4][64 * 128];
    __shared__ int eids[TILE];

    const int tid = threadIdx.x;
    if (tid < TILE) eids[tid] = (tid < ne) ? bond_edges[base + t0 + tid] : 0;
    __syncthreads();

    for (int i = tid; i < 1024; i += 256) {
        const int el = i >> 4, u = i & 15;
        uint4 v = make_uint4(0, 0, 0, 0);
        if (el < ne) {
            const int e = eids[el];
            int s, d;
            if (e < Ep) { s = src[e]; d = dst[e]; }
            else        { s = dst[e - Ep]; d = src[e - Ep]; }
            v = (u < 8) ? ((const uint4*)(Qbf + s * 64))[u]
                        : ((const uint4*)(Kbf + d * 64))[u - 8];
        }
        const int b = (el << 8) + (u << 4);
        *(uint4*)(xs + (b ^ ((el & 7) << 4))) = v;
    }
    __syncthreads();

    const int lane = tid & 63;
    const int h = tid >> 6;
    const int bh = bt * H + h;
    const int lg = lane >> 4;
    const int lr = lane & 15;

    f32x4 acc[4][4];
    const float* bb0 = b0 + bh * 64;
#pragma unroll
    for (int nt = 0; nt < 4; ++nt) {
        const float bv = bb0[(nt << 4) + lr];
#pragma unroll
        for (int mt = 0; mt < 4; ++mt) acc[mt][nt] = (f32x4){bv, bv, bv, bv};
    }
    const short8* W0f = (const short8*)W0p + (size_t)bh * 1024;
#pragma unroll
    for (int ks = 0; ks < 4; ++ks) {
        short8 a[4];
        const int koff = (ks << 6) + (lg << 4);
#pragma unroll
        for (int mt = 0; mt < 4; ++mt) {
            const int row = (mt << 4) + lr;
            const int b = (row << 8) + koff;
            a[mt] = *(const short8*)(xs + (b ^ ((row & 7) << 4)));
        }
        short8 bfr[4];
#pragma unroll
        for (int nt = 0; nt < 4; ++nt) bfr[nt] = W0f[(((ks << 2) + nt) << 6) + lane];
#pragma unroll
        for (int mt = 0; mt < 4; ++mt)
#pragma unroll
            for (int nt = 0; nt < 4; ++nt)
                acc[mt][nt] = __builtin_amdgcn_mfma_f32_16x16x32_bf16(a[mt], bfr[nt], acc[mt][nt], 0, 0, 0);
    }
    unsigned char* h0 = h0s[h];
#pragma unroll
    for (int mt = 0; mt < 4; ++mt)
#pragma unroll
        for (int nt = 0; nt < 4; ++nt)
#pragma unroll
            for (int r = 0; r < 4; ++r) {
                const int row = (mt << 4) + (lg << 2) + r;
                const int col = (nt << 4) + lr;
                const int b = (row << 7) + (col << 1);
                *(unsigned short*)(h0 + (b ^ ((row & 7) << 4))) = f2bf(fmaxf(acc[mt][nt][r], 0.f));
            }

    f32x4 acc1[4][4];
    const float* bb1 = b1 + bh * 64;
#pragma unroll
    for (int nt = 0; nt < 4; ++nt) {
        const float bv = bb1[(nt << 4) + lr];
#pragma unroll
        for (int mt = 0; mt < 4; ++mt) acc1[mt][nt] = (f32x4){bv, bv, bv, bv};
    }
    const short8* W1f = (const short8*)W1p + (size_t)bh * 512;
#pragma unroll
    for (int ks = 0; ks < 2; ++ks) {
        short8 a[4];
        const int koff = (ks << 6) + (lg << 4);
#pragma unroll
        for (int mt = 0; mt < 4; ++mt) {
            const int row = (mt << 4) + lr;
            const int b = (row << 7) + koff;
            a[mt] = *(const short8*)(h0 + (b ^ ((row & 7) << 4)));
        }
        short8 bfr[4];
#pragma unroll
        for (int nt = 0; nt < 4; ++nt) bfr[nt] = W1f[(((ks << 2) + nt) << 6) + lane];
#pragma unroll
        for (int mt = 0; mt < 4; ++mt)
#pragma unroll
            for (int nt = 0; nt < 4; ++nt)
                acc1[mt][nt] = __builtin_amdgcn_mfma_f32_16x16x32_bf16(a[mt], bfr[nt], acc1[mt][nt], 0, 0, 0);
    }

    const float* w2 = W2 + bh * 64;
    float w2v[4];
#pragma unroll
    for (int nt = 0; nt < 4; ++nt) w2v[nt] = w2[(nt << 4) + lr];
    float p[4][4];
#pragma unroll
    for (int mt = 0; mt < 4; ++mt)
#pragma unroll
        for (int r = 0; r < 4; ++r) {
            float s = 0.f;
#pragma unroll
            for (int nt = 0; nt < 4; ++nt) s += fmaxf(acc1[mt][nt][r], 0.f) * w2v[nt];
            p[mt][r] = s;
        }
#pragma unroll
    for (int off = 1; off <= 8; off <<= 1)
#pragma unroll
        for (int mt = 0; mt < 4; ++mt)
#pragma unroll
            for (int r = 0; r < 4; ++r) p[mt][r] += __shfl_xor(p[mt][r], off, 64);
    const int e_w = ((lr >> 2) << 4) + (lg << 2) + (lr & 3);
    float sc = p[lr >> 2][lr & 3] + b2[bh];
    sc = sc > 0.f ? sc : NEG_SLOPE * sc;
    if (e_w < ne) scores[(size_t)eids[e_w] * H + h] = sc;
}

__global__ __launch_bounds__(256) void agg_kernel(
    const float* __restrict__ V, const float* __restrict__ scores,
    const int* __restrict__ rowStart, const int* __restrict__ edge_col,
    const int* __restrict__ edge_eid, const float* __restrict__ Pw,
    const float* __restrict__ Pb, float* __restrict__ out)
{
    const int row = blockIdx.x;
    const int tid = threadIdx.x;
    const int lane = tid & 63;
    const int h = tid >> 6;
    const int beg = rowStart[row];
    int deg = rowStart[row + 1] - beg;
    if (deg > MAXDEG) deg = MAXDEG;

    __shared__ int tcol[MAXDEG], teid[MAXDEG];
    __shared__ int scol[MAXDEG], seid[MAXDEG];
    __shared__ int win[MAXDEG];
    __shared__ float wgt[4][MAXDEG];
    __shared__ float r[256];
    __shared__ float part2[4][64];

    for (int a = tid; a < deg; a += 256) { tcol[a] = edge_col[beg + a]; teid[a] = edge_eid[beg + a]; }
    __syncthreads();
    for (int a = tid; a < deg; a += 256) {
        const int e = teid[a];
        int rk = 0;
        for (int b = 0; b < deg; ++b) rk += (teid[b] < e);
        scol[rk] = tcol[a];
        seid[rk] = e;
    }
    __syncthreads();
    for (int a = tid; a < deg; a += 256) {
        const int c = scol[a];
        int wn = 1;
        for (int b = a + 1; b < deg; ++b) if (scol[b] == c) { wn = 0; break; }
        win[a] = wn;
    }
    __syncthreads();

    float m = -1e30f;
    for (int a = lane; a < deg; a += 64)
        if (win[a]) m = fmaxf(m, scores[(size_t)seid[a] * H + h]);
#pragma unroll
    for (int off = 32; off; off >>= 1) m = fmaxf(m, __shfl_xor(m, off, 64));

    float dn = 0.f;
    for (int a = lane; a < deg; a += 64) {
        const float wv = win[a] ? __expf(scores[(size_t)seid[a] * H + h] - m) : 0.f;
        wgt[h][a] = wv;
        dn += wv;
    }
#pragma unroll
    for (int off = 32; off; off >>= 1) dn += __shfl_xor(dn, off, 64);

    float accv = 0.f;
    for (int a = 0; a < deg; ++a) {
        const float wv = wgt[h][a];
        if (wv != 0.f) accv += wv * V[(size_t)scol[a] * D + lane];
    }
    r[tid] = accv / dn;
    __syncthreads();
    {
        float s = 0.f;
#pragma unroll 8
        for (int k = 0; k < 64; ++k) s += r[h * 64 + k] * Pw[(h * 64 + k) * D + lane];
        part2[h][lane] = s;
    }
    __syncthreads();
    if (tid < 64)
        out[(size_t)row * D + tid] = part2[0][tid] + part2[1][tid] + part2[2][tid] + part2[3][tid] + Pb[tid];
}

// ======================= launch =======================
extern "C" void kernel_launch(void* const* d_in, const int* in_sizes, int n_in,
                              void* d_out, int out_size, void* d_ws, size_t ws_size,
                              hipStream_t stream)
{
    const float* emb = (const float*)d_in[0];
    const float* Qw  = (const float*)d_in[1];
    const float* Qb  = (const float*)d_in[2];
    const float* Kw  = (const float*)d_in[3];
    const float* Kb  = (const float*)d_in[4];
    const float* Vw  = (const float*)d_in[5];
    const float* Vb  = (const float*)d_in[6];
    const float* W0  = (const float*)d_in[7];
    const float* b0  = (const float*)d_in[8];
    const float* W1  = (const float*)d_in[9];
    const float* b1  = (const float*)d_in[10];
    const float* W2  = (const float*)d_in[11];
    const float* b2  = (const float*)d_in[12];
    const float* Pw  = (const float*)d_in[13];
    const float* Pb  = (const float*)d_in[14];
    const int* src   = (const int*)d_in[15];
    const int* dst   = (const int*)d_in[16];
    const int* bond  = (const int*)d_in[17];

    const int N  = in_sizes[0] / D;
    const int Ep = in_sizes[15];
    const int TE = 2 * Ep;
    const int nblk = (TE + 255) / 256;
    const int nq = (N + 3) / 4;
    const int ntileCap = (TE >> 6) + NB + 8;

    char* w = (char*)d_ws;
    auto alloc = [&](size_t bytes) -> void* {
        void* p = (void*)w;
        w += ((bytes + 255) / 256) * 256;
        return p;
    };
    unsigned short* Qbf = (unsigned short*)alloc((size_t)N * D * 2);
    unsigned short* Kbf = (unsigned short*)alloc((size_t)N * D * 2);
    float* V        = (float*)alloc((size_t)N * D * 4);
    unsigned short* W0p = (unsigned short*)alloc((size_t)131072 * 2);
    unsigned short* W1p = (unsigned short*)alloc((size_t)65536 * 2);
    float* scores   = (float*)alloc((size_t)TE * H * 4);
    int* rowStart   = (int*)alloc((size_t)(N + 1) * 4);
    int* bondOff    = (int*)alloc((size_t)(NB + 1) * 4);
    int* edge_col   = (int*)alloc((size_t)TE * 4);
    int* edge_eid   = (int*)alloc((size_t)TE * 4);
    int* bond_edges = (int*)alloc((size_t)TE * 4);
    int* blockBondCnt  = (int*)alloc((size_t)NB * nblk * 4);
    int* blockBondBase = (int*)alloc((size_t)NB * nblk * 4);
    int* counters   = (int*)alloc((size_t)(2 * N) * 4);
    int* tileBt     = (int*)alloc((size_t)ntileCap * 4);
    int* tileT0     = (int*)alloc((size_t)ntileCap * 4);
    int* ntiles     = (int*)alloc(256);
    if ((size_t)(w - (char*)d_ws) > ws_size) return;

    int* rowCnt  = counters;
    int* rowFill = counters + N;

    MegaParams mp;
    mp.emb = emb; mp.Qw = Qw; mp.Qb = Qb; mp.Kw = Kw; mp.Kb = Kb; mp.Vw = Vw; mp.Vb = Vb;
    mp.W0 = W0; mp.b0 = b0; mp.W1 = W1; mp.b1 = b1; mp.W2 = W2; mp.b2 = b2; mp.Pw = Pw; mp.Pb = Pb;
    mp.src = src; mp.dst = dst; mp.bond = bond;
    mp.Qbf = Qbf; mp.Kbf = Kbf; mp.W0p = W0p; mp.W1p = W1p;
    mp.V = V; mp.scores = scores; mp.out = (float*)d_out;
    mp.rowStart = rowStart; mp.bondOff = bondOff; mp.edge_col = edge_col; mp.edge_eid = edge_eid;
    mp.bond_edges = bond_edges; mp.blockBondCnt = blockBondCnt; mp.blockBondBase = blockBondBase;
    mp.counters = counters; mp.tileBt = tileBt; mp.tileT0 = tileT0; mp.ntiles = ntiles;
    mp.N = N; mp.Ep = Ep; mp.TE = TE; mp.nblk = nblk; mp.nq = nq;

    void* kargs[] = { &mp };
    hipError_t rc = hipLaunchCooperativeKernel((const void*)mega_kernel, dim3(512), dim3(256),
                                               kargs, 0, stream);
    if (rc == hipSuccess) return;

    // -------- fallback: proven multi-kernel path --------
    prep_kernel<<<nq + 512, 256, 0, stream>>>(emb, Qw, Qb, Kw, Kb, Vw, Vb, Qbf, Kbf, V,
                                              W0, W1, W0p, W1p, counters, N, nq);
    count_kernel<<<nblk, 256, 0, stream>>>(src, dst, bond, Ep, rowCnt, blockBondCnt, nblk);
    scan_kernel<<<1, 1024, 0, stream>>>(rowCnt, rowStart, blockBondCnt, blockBondBase,
                                        bondOff, N, nblk, tileBt, tileT0, ntiles);
    scatter_kernel<<<nblk, 256, 0, stream>>>(src, dst, bond, Ep, rowStart, rowFill,
                                             blockBondBase, nblk, edge_col, edge_eid,
                                             bond_edges);
    dim3 mgrid((TE + TILE - 1) / TILE, NB);
    mlp_kernel<<<mgrid, 256, 0, stream>>>(Qbf, Kbf, src, dst, Ep, bondOff, bond_edges,
                                          W0p, W1p, b0, b1, W2, b2, scores);
    agg_kernel<<<N, 256, 0, stream>>>(V, scores, rowStart, edge_col, edge_eid, Pw, Pb,
                                      (float*)d_out);
}

// Round 7
// 78.197 us; speedup vs baseline: 5.4759x; 5.4759x over previous
//
#include <hip/hip_runtime.h>
#include <hip/hip_bf16.h>
#include <math.h>

#define D 64
#define H 4
#define NB 4
#define TILE 64
#define PAD 128
#define NEG_SLOPE 0.2f

typedef __attribute__((ext_vector_type(8))) short short8;
typedef __attribute__((ext_vector_type(4))) float f32x4;

__device__ __forceinline__ unsigned short f2bf(float f) {
    union { float f; unsigned int u; } c; c.f = f;
    const unsigned int u = c.u;
    return (unsigned short)((u + 0x7fffu + ((u >> 16) & 1u)) >> 16);
}

// ---- prep: [0,nq) zero rowFill + QKV ; [nq,nq+512) weight prepack ; [nq+512,..) bond histogram ----
__global__ __launch_bounds__(256) void prep_kernel(
    const float* __restrict__ emb,
    const float* __restrict__ Qw, const float* __restrict__ Qb,
    const float* __restrict__ Kw, const float* __restrict__ Kb,
    const float* __restrict__ Vw, const float* __restrict__ Vb,
    unsigned short* __restrict__ Qbf, unsigned short* __restrict__ Kbf,
    float* __restrict__ V,
    const float* __restrict__ W0, const float* __restrict__ W1,
    unsigned short* __restrict__ W0p, unsigned short* __restrict__ W1p,
    const int* __restrict__ bond, int Ep, int TE,
    int* __restrict__ rowFill, int* __restrict__ blockBondCnt, int nblk,
    int N, int nq)
{
    const int tid = threadIdx.x;
    const int bid = blockIdx.x;
    if (bid < nq) {
        const int gz = bid * 256 + tid;
        if (gz < N) rowFill[gz] = 0;
        __shared__ float e[4][64];
        const int n = bid * 4 + (tid >> 6);
        const int d = tid & 63;
        if (n < N) e[tid >> 6][d] = emb[n * D + d];
        __syncthreads();
        if (n < N) {
            float aq = Qb[d], ak = Kb[d], av = Vb[d];
            const float* er = e[tid >> 6];
#pragma unroll 8
            for (int k = 0; k < D; ++k) {
                const float x = er[k];
                aq += x * Qw[k * D + d];
                ak += x * Kw[k * D + d];
                av += x * Vw[k * D + d];
            }
            Qbf[n * D + d] = f2bf(aq);
            Kbf[n * D + d] = f2bf(ak);
            V[n * D + d] = av;
        }
    } else if (bid < nq + 512) {
        const int idx = (bid - nq) * 256 + tid;   // < 131072
        {
            const int j = idx & 7, ln = (idx >> 3) & 63, nt = (idx >> 9) & 3;
            const int ks = (idx >> 11) & 3, bh = idx >> 13;
            const int k = ks * 32 + ((ln >> 4) << 3) + j;
            const int nn = (nt << 4) + (ln & 15);
            W0p[idx] = f2bf(W0[((size_t)bh * 128 + k) * 64 + nn]);
        }
        if (idx < 65536) {
            const int j = idx & 7, ln = (idx >> 3) & 63, nt = (idx >> 9) & 3;
            const int ks = (idx >> 11) & 1, bh = idx >> 12;
            const int k = ks * 32 + ((ln >> 4) << 3) + j;
            const int nn = (nt << 4) + (ln & 15);
            W1p[idx] = f2bf(W1[((size_t)bh * 64 + k) * 64 + nn]);
        }
    } else {
        __shared__ int wcnt[4][NB];
        const int vb = bid - nq - 512;
        const int e = vb * 256 + tid;
        const int lane = tid & 63, wave = tid >> 6;
        int bt = -1;
        if (e < TE) bt = (e < Ep) ? bond[e] : bond[e - Ep];
#pragma unroll
        for (int t = 0; t < NB; ++t) {
            const unsigned long long m = __ballot(bt == t);
            if (lane == 0) wcnt[wave][t] = (int)__popcll(m);
        }
        __syncthreads();
        if (tid < NB) {
            int s = 0;
#pragma unroll
            for (int w = 0; w < 4; ++w) s += wcnt[w][tid];
            blockBondCnt[tid * nblk + vb] = s;
        }
    }
}

// ---- scatter: in-block scan of blockBondCnt -> bases; padded row lists + bond buckets ----
__global__ __launch_bounds__(256) void scatter_kernel(
    const int* __restrict__ src, const int* __restrict__ dst,
    const int* __restrict__ bond, int Ep, int TE, int nblk,
    const int* __restrict__ blockBondCnt, int* __restrict__ rowFill,
    int* __restrict__ edge_col, int* __restrict__ edge_eid,
    int* __restrict__ padPos, int* __restrict__ bond_edges, int* __restrict__ bondOff)
{
    __shared__ int chunkpre[256];
    __shared__ int base_lds[NB];
    __shared__ int wcnt[4][NB], wbase[4][NB];
    const int tid = threadIdx.x;
    const int vb = blockIdx.x;
    const int M = NB * nblk;
    const int c = (M + 255) >> 8;

    // block-local exclusive scan over flattened [t][vb'] histogram
    int s = 0;
    for (int i = 0; i < c; ++i) { const int idx = tid * c + i; if (idx < M) s += blockBondCnt[idx]; }
    chunkpre[tid] = s;
    __syncthreads();
    int val = s;
    for (int off = 1; off < 256; off <<= 1) {
        const int o = (tid >= off) ? chunkpre[tid - off] : 0;
        __syncthreads();
        val += o;
        chunkpre[tid] = val;
        __syncthreads();
    }
    int excl = val - s;
    for (int i = 0; i < c; ++i) {
        const int idx = tid * c + i;
        if (idx < M) {
            const int t = idx / nblk, r = idx - t * nblk;
            if (r == vb) base_lds[t] = excl;
            if (vb == 0 && r == 0) bondOff[t] = excl;
            excl += blockBondCnt[idx];
        }
    }
    if (vb == 0 && tid == 255) bondOff[NB] = chunkpre[255];
    __syncthreads();

    // scatter
    const int lane = tid & 63, wave = tid >> 6;
    const int e = vb * 256 + tid;
    const bool act = (e < TE);
    int sN = 0, dN = 0, bt = -1;
    if (act) {
        if (e < Ep) { sN = src[e]; dN = dst[e]; bt = bond[e]; }
        else        { sN = dst[e - Ep]; dN = src[e - Ep]; bt = bond[e - Ep]; }
        const int p = atomicAdd(&rowFill[sN], 1);
        if (p < PAD) {
            edge_col[sN * PAD + p] = dN;
            edge_eid[sN * PAD + p] = e;
            padPos[e] = sN * PAD + p;
        } else padPos[e] = -1;
    }
    int myrank = 0;
#pragma unroll
    for (int t = 0; t < NB; ++t) {
        const unsigned long long m = __ballot(bt == t);
        if (lane == 0) wcnt[wave][t] = (int)__popcll(m);
        if (bt == t) myrank = (int)__popcll(m & ((1ull << lane) - 1ull));
    }
    __syncthreads();
    if (tid < NB) {
        int sum = 0;
#pragma unroll
        for (int w = 0; w < 4; ++w) { wbase[w][tid] = sum; sum += wcnt[w][tid]; }
    }
    __syncthreads();
    if (act) bond_edges[base_lds[bt] + wbase[wave][bt] + myrank] = e;
}

// ---- MFMA grouped edge MLP: scores written to row-slot order via padPos ----
__global__ __launch_bounds__(256) void mlp_kernel(
    const unsigned short* __restrict__ Qbf, const unsigned short* __restrict__ Kbf,
    const int* __restrict__ src, const int* __restrict__ dst, int Ep,
    const int* __restrict__ bondOff, const int* __restrict__ bond_edges,
    const int* __restrict__ padPos,
    const unsigned short* __restrict__ W0p, const unsigned short* __restrict__ W1p,
    const float* __restrict__ b0, const float* __restrict__ b1,
    const float* __restrict__ W2, const float* __restrict__ b2,
    float* __restrict__ S)
{
    const int bt = blockIdx.y;
    const int base = bondOff[bt];
    const int cnt  = bondOff[bt + 1] - base;
    const int t0 = blockIdx.x * TILE;
    if (t0 >= cnt) return;
    const int ne = min(TILE, cnt - t0);

    __shared__ __align__(16) unsigned char xs[64 * 256];
    __shared__ __align__(16) unsigned char h0s[4][64 * 128];
    __shared__ int eids[TILE];

    const int tid = threadIdx.x;
    if (tid < TILE) eids[tid] = (tid < ne) ? bond_edges[base + t0 + tid] : 0;
    __syncthreads();

    for (int i = tid; i < 1024; i += 256) {
        const int el = i >> 4, u = i & 15;
        uint4 v = make_uint4(0, 0, 0, 0);
        if (el < ne) {
            const int e = eids[el];
            int s, d;
            if (e < Ep) { s = src[e]; d = dst[e]; }
            else        { s = dst[e - Ep]; d = src[e - Ep]; }
            v = (u < 8) ? ((const uint4*)(Qbf + s * 64))[u]
                        : ((const uint4*)(Kbf + d * 64))[u - 8];
        }
        const int b = (el << 8) + (u << 4);
        *(uint4*)(xs + (b ^ ((el & 7) << 4))) = v;
    }
    __syncthreads();

    const int lane = tid & 63;
    const int h = tid >> 6;
    const int bh = bt * H + h;
    const int lg = lane >> 4;
    const int lr = lane & 15;

    f32x4 acc[4][4];
    const float* bb0 = b0 + bh * 64;
#pragma unroll
    for (int nt = 0; nt < 4; ++nt) {
        const float bv = bb0[(nt << 4) + lr];
#pragma unroll
        for (int mt = 0; mt < 4; ++mt) acc[mt][nt] = (f32x4){bv, bv, bv, bv};
    }
    const short8* W0f = (const short8*)W0p + (size_t)bh * 1024;
#pragma unroll
    for (int ks = 0; ks < 4; ++ks) {
        short8 a[4];
        const int koff = (ks << 6) + (lg << 4);
#pragma unroll
        for (int mt = 0; mt < 4; ++mt) {
            const int row = (mt << 4) + lr;
            const int b = (row << 8) + koff;
            a[mt] = *(const short8*)(xs + (b ^ ((row & 7) << 4)));
        }
        short8 bfr[4];
#pragma unroll
        for (int nt = 0; nt < 4; ++nt) bfr[nt] = W0f[(((ks << 2) + nt) << 6) + lane];
#pragma unroll
        for (int mt = 0; mt < 4; ++mt)
#pragma unroll
            for (int nt = 0; nt < 4; ++nt)
                acc[mt][nt] = __builtin_amdgcn_mfma_f32_16x16x32_bf16(a[mt], bfr[nt], acc[mt][nt], 0, 0, 0);
    }
    unsigned char* h0 = h0s[h];
#pragma unroll
    for (int mt = 0; mt < 4; ++mt)
#pragma unroll
        for (int nt = 0; nt < 4; ++nt)
#pragma unroll
            for (int r = 0; r < 4; ++r) {
                const int row = (mt << 4) + (lg << 2) + r;
                const int col = (nt << 4) + lr;
                const int b = (row << 7) + (col << 1);
                *(unsigned short*)(h0 + (b ^ ((row & 7) << 4))) = f2bf(fmaxf(acc[mt][nt][r], 0.f));
            }

    f32x4 acc1[4][4];
    const float* bb1 = b1 + bh * 64;
#pragma unroll
    for (int nt = 0; nt < 4; ++nt) {
        const float bv = bb1[(nt << 4) + lr];
#pragma unroll
        for (int mt = 0; mt < 4; ++mt) acc1[mt][nt] = (f32x4){bv, bv, bv, bv};
    }
    const short8* W1f = (const short8*)W1p + (size_t)bh * 512;
#pragma unroll
    for (int ks = 0; ks < 2; ++ks) {
        short8 a[4];
        const int koff = (ks << 6) + (lg << 4);
#pragma unroll
        for (int mt = 0; mt < 4; ++mt) {
            const int row = (mt << 4) + lr;
            const int b = (row << 7) + koff;
            a[mt] = *(const short8*)(h0 + (b ^ ((row & 7) << 4)));
        }
        short8 bfr[4];
#pragma unroll
        for (int nt = 0; nt < 4; ++nt) bfr[nt] = W1f[(((ks << 2) + nt) << 6) + lane];
#pragma unroll
        for (int mt = 0; mt < 4; ++mt)
#pragma unroll
            for (int nt = 0; nt < 4; ++nt)
                acc1[mt][nt] = __builtin_amdgcn_mfma_f32_16x16x32_bf16(a[mt], bfr[nt], acc1[mt][nt], 0, 0, 0);
    }

    const float* w2 = W2 + bh * 64;
    float w2v[4];
#pragma unroll
    for (int nt = 0; nt < 4; ++nt) w2v[nt] = w2[(nt << 4) + lr];
    float p[4][4];
#pragma unroll
    for (int mt = 0; mt < 4; ++mt)
#pragma unroll
        for (int r = 0; r < 4; ++r) {
            float s = 0.f;
#pragma unroll
            for (int nt = 0; nt < 4; ++nt) s += fmaxf(acc1[mt][nt][r], 0.f) * w2v[nt];
            p[mt][r] = s;
        }
#pragma unroll
    for (int off = 1; off <= 8; off <<= 1)
#pragma unroll
        for (int mt = 0; mt < 4; ++mt)
#pragma unroll
            for (int r = 0; r < 4; ++r) p[mt][r] += __shfl_xor(p[mt][r], off, 64);
    const int e_w = ((lr >> 2) << 4) + (lg << 2) + (lr & 3);
    float sc = p[lr >> 2][lr & 3] + b2[bh];
    sc = sc > 0.f ? sc : NEG_SLOPE * sc;
    if (e_w < ne) {
        const int pp = padPos[eids[e_w]];
        if (pp >= 0) S[(size_t)pp * H + h] = sc;
    }
}

// ---- agg: padded rows, row-local score reads, fused projection ----
__global__ __launch_bounds__(256) void agg_kernel(
    const float* __restrict__ V, const float* __restrict__ S,
    const int* __restrict__ rowFill,
    const int* __restrict__ edge_col, const int* __restrict__ edge_eid,
    const float* __restrict__ Pw, const float* __restrict__ Pb, float* __restrict__ out)
{
    const int row = blockIdx.x;
    const int tid = threadIdx.x;
    const int lane = tid & 63;
    const int h = tid >> 6;
    const int beg = row * PAD;
    int deg = rowFill[row];
    if (deg > PAD) deg = PAD;

    __shared__ int tcol[PAD], teid[PAD], scol[PAD], spos[PAD], win[PAD];
    __shared__ float wgt[4][PAD];
    __shared__ float rr[256];
    __shared__ float part2[4][64];

    for (int a = tid; a < deg; a += 256) { tcol[a] = edge_col[beg + a]; teid[a] = edge_eid[beg + a]; }
    __syncthreads();
    for (int a = tid; a < deg; a += 256) {
        const int e = teid[a];
        int r = 0;
        for (int b = 0; b < deg; ++b) r += (teid[b] < e);
        scol[r] = tcol[a];
        spos[r] = a;
    }
    __syncthreads();
    for (int a = tid; a < deg; a += 256) {
        const int c = scol[a];
        int wn = 1;
        for (int b = a + 1; b < deg; ++b) if (scol[b] == c) { wn = 0; break; }
        win[a] = wn;
    }
    __syncthreads();

    float m = -1e30f;
    for (int a = lane; a < deg; a += 64)
        if (win[a]) m = fmaxf(m, S[(size_t)(beg + spos[a]) * H + h]);
#pragma unroll
    for (int off = 32; off; off >>= 1) m = fmaxf(m, __shfl_xor(m, off, 64));

    float dn = 0.f;
    for (int a = lane; a < deg; a += 64) {
        const float wv = win[a] ? __expf(S[(size_t)(beg + spos[a]) * H + h] - m) : 0.f;
        wgt[h][a] = wv;
        dn += wv;
    }
#pragma unroll
    for (int off = 32; off; off >>= 1) dn += __shfl_xor(dn, off, 64);

    float accv = 0.f;
    for (int a = 0; a < deg; ++a) accv += wgt[h][a] * V[(size_t)scol[a] * D + lane];
    rr[tid] = accv / dn;
    __syncthreads();
    {
        float sps = 0.f;
#pragma unroll 8
        for (int k = 0; k < 64; ++k) sps += rr[h * 64 + k] * Pw[(h * 64 + k) * D + lane];
        part2[h][lane] = sps;
    }
    __syncthreads();
    if (tid < 64)
        out[(size_t)row * D + tid] = part2[0][tid] + part2[1][tid] + part2[2][tid] + part2[3][tid] + Pb[tid];
}

extern "C" void kernel_launch(void* const* d_in, const int* in_sizes, int n_in,
                              void* d_out, int out_size, void* d_ws, size_t ws_size,
                              hipStream_t stream)
{
    const float* emb = (const float*)d_in[0];
    const float* Qw  = (const float*)d_in[1];
    const float* Qb  = (const float*)d_in[2];
    const float* Kw  = (const float*)d_in[3];
    const float* Kb  = (const float*)d_in[4];
    const float* Vw  = (const float*)d_in[5];
    const float* Vb  = (const float*)d_in[6];
    const float* W0  = (const float*)d_in[7];
    const float* b0  = (const float*)d_in[8];
    const float* W1  = (const float*)d_in[9];
    const float* b1  = (const float*)d_in[10];
    const float* W2  = (const float*)d_in[11];
    const float* b2  = (const float*)d_in[12];
    const float* Pw  = (const float*)d_in[13];
    const float* Pb  = (const float*)d_in[14];
    const int* src   = (const int*)d_in[15];
    const int* dst   = (const int*)d_in[16];
    const int* bond  = (const int*)d_in[17];

    const int N  = in_sizes[0] / D;
    const int Ep = in_sizes[15];
    const int TE = 2 * Ep;
    const int nblk = (TE + 255) / 256;
    const int nq = (N + 3) / 4;

    char* w = (char*)d_ws;
    auto alloc = [&](size_t bytes) -> void* {
        void* p = (void*)w;
        w += ((bytes + 255) / 256) * 256;
        return p;
    };
    unsigned short* Qbf = (unsigned short*)alloc((size_t)N * D * 2);
    unsigned short* Kbf = (unsigned short*)alloc((size_t)N * D * 2);
    float* V        = (float*)alloc((size_t)N * D * 4);
    unsigned short* W0p = (unsigned short*)alloc((size_t)131072 * 2);
    unsigned short* W1p = (unsigned short*)alloc((size_t)65536 * 2);
    float* S        = (float*)alloc((size_t)N * PAD * H * 4);
    int* edge_col   = (int*)alloc((size_t)N * PAD * 4);
    int* edge_eid   = (int*)alloc((size_t)N * PAD * 4);
    int* bond_edges = (int*)alloc((size_t)TE * 4);
    int* padPos     = (int*)alloc((size_t)TE * 4);
    int* blockBondCnt = (int*)alloc((size_t)NB * nblk * 4);
    int* bondOff    = (int*)alloc((size_t)(NB + 1) * 4);
    int* rowFill    = (int*)alloc((size_t)N * 4);
    if ((size_t)(w - (char*)d_ws) > ws_size) return;

    prep_kernel<<<nq + 512 + nblk, 256, 0, stream>>>(
        emb, Qw, Qb, Kw, Kb, Vw, Vb, Qbf, Kbf, V, W0, W1, W0p, W1p,
        bond, Ep, TE, rowFill, blockBondCnt, nblk, N, nq);
    scatter_kernel<<<nblk, 256, 0, stream>>>(
        src, dst, bond, Ep, TE, nblk, blockBondCnt, rowFill,
        edge_col, edge_eid, padPos, bond_edges, bondOff);
    dim3 mgrid((TE + TILE - 1) / TILE, NB);
    mlp_kernel<<<mgrid, 256, 0, stream>>>(
        Qbf, Kbf, src, dst, Ep, bondOff, bond_edges, padPos,
        W0p, W1p, b0, b1, W2, b2, S);
    agg_kernel<<<N, 256, 0, stream>>>(
        V, S, rowFill, edge_col, edge_eid, Pw, Pb, (float*)d_out);
}

// Round 8
// 77.914 us; speedup vs baseline: 5.4958x; 1.0036x over previous
//
#include <hip/hip_runtime.h>
#include <hip/hip_bf16.h>
#include <math.h>

#define D 64
#define H 4
#define NB 4
#define TILE 64
#define PAD 128
#define NEG_SLOPE 0.2f

typedef __attribute__((ext_vector_type(8))) short short8;
typedef __attribute__((ext_vector_type(4))) float f32x4;

__device__ __forceinline__ unsigned short f2bf(float f) {
    union { float f; unsigned int u; } c; c.f = f;
    const unsigned int u = c.u;
    return (unsigned short)((u + 0x7fffu + ((u >> 16) & 1u)) >> 16);
}

// ---- prep: [0,nq) zero rowFill + QKV ; [nq,nq+512) weight prepack ; [nq+512,..) bond histogram ----
__global__ __launch_bounds__(256) void prep_kernel(
    const float* __restrict__ emb,
    const float* __restrict__ Qw, const float* __restrict__ Qb,
    const float* __restrict__ Kw, const float* __restrict__ Kb,
    const float* __restrict__ Vw, const float* __restrict__ Vb,
    unsigned short* __restrict__ Qbf, unsigned short* __restrict__ Kbf,
    float* __restrict__ V,
    const float* __restrict__ W0, const float* __restrict__ W1,
    unsigned short* __restrict__ W0p, unsigned short* __restrict__ W1p,
    const int* __restrict__ bond, int Ep, int TE,
    int* __restrict__ rowFill, int* __restrict__ blockBondCnt, int nblk,
    int N, int nq)
{
    const int tid = threadIdx.x;
    const int bid = blockIdx.x;
    if (bid < nq) {
        const int gz = bid * 256 + tid;
        if (gz < N) rowFill[gz] = 0;
        __shared__ float e[4][64];
        const int n = bid * 4 + (tid >> 6);
        const int d = tid & 63;
        if (n < N) e[tid >> 6][d] = emb[n * D + d];
        __syncthreads();
        if (n < N) {
            float aq = Qb[d], ak = Kb[d], av = Vb[d];
            const float* er = e[tid >> 6];
#pragma unroll 8
            for (int k = 0; k < D; ++k) {
                const float x = er[k];
                aq += x * Qw[k * D + d];
                ak += x * Kw[k * D + d];
                av += x * Vw[k * D + d];
            }
            Qbf[n * D + d] = f2bf(aq);
            Kbf[n * D + d] = f2bf(ak);
            V[n * D + d] = av;
        }
    } else if (bid < nq + 512) {
        const int idx = (bid - nq) * 256 + tid;   // < 131072
        {
            const int j = idx & 7, ln = (idx >> 3) & 63, nt = (idx >> 9) & 3;
            const int ks = (idx >> 11) & 3, bh = idx >> 13;
            const int k = ks * 32 + ((ln >> 4) << 3) + j;
            const int nn = (nt << 4) + (ln & 15);
            W0p[idx] = f2bf(W0[((size_t)bh * 128 + k) * 64 + nn]);
        }
        if (idx < 65536) {
            const int j = idx & 7, ln = (idx >> 3) & 63, nt = (idx >> 9) & 3;
            const int ks = (idx >> 11) & 1, bh = idx >> 12;
            const int k = ks * 32 + ((ln >> 4) << 3) + j;
            const int nn = (nt << 4) + (ln & 15);
            W1p[idx] = f2bf(W1[((size_t)bh * 64 + k) * 64 + nn]);
        }
    } else {
        __shared__ int wcnt[4][NB];
        const int vb = bid - nq - 512;
        const int e = vb * 256 + tid;
        const int lane = tid & 63, wave = tid >> 6;
        int bt = -1;
        if (e < TE) bt = (e < Ep) ? bond[e] : bond[e - Ep];
#pragma unroll
        for (int t = 0; t < NB; ++t) {
            const unsigned long long m = __ballot(bt == t);
            if (lane == 0) wcnt[wave][t] = (int)__popcll(m);
        }
        __syncthreads();
        if (tid < NB) {
            int s = 0;
#pragma unroll
            for (int w = 0; w < 4; ++w) s += wcnt[w][tid];
            blockBondCnt[tid * nblk + vb] = s;
        }
    }
}

// ---- scatter: in-block scan of blockBondCnt -> bases; padded row lists + bond buckets ----
__global__ __launch_bounds__(256) void scatter_kernel(
    const int* __restrict__ src, const int* __restrict__ dst,
    const int* __restrict__ bond, int Ep, int TE, int nblk,
    const int* __restrict__ blockBondCnt, int* __restrict__ rowFill,
    int* __restrict__ edge_col, int* __restrict__ edge_eid,
    int* __restrict__ padPos, int* __restrict__ bond_edges, int* __restrict__ bondOff)
{
    __shared__ int chunkpre[256];
    __shared__ int base_lds[NB];
    __shared__ int wcnt[4][NB], wbase[4][NB];
    const int tid = threadIdx.x;
    const int vb = blockIdx.x;
    const int M = NB * nblk;
    const int c = (M + 255) >> 8;

    int s = 0;
    for (int i = 0; i < c; ++i) { const int idx = tid * c + i; if (idx < M) s += blockBondCnt[idx]; }
    chunkpre[tid] = s;
    __syncthreads();
    int val = s;
    for (int off = 1; off < 256; off <<= 1) {
        const int o = (tid >= off) ? chunkpre[tid - off] : 0;
        __syncthreads();
        val += o;
        chunkpre[tid] = val;
        __syncthreads();
    }
    int excl = val - s;
    for (int i = 0; i < c; ++i) {
        const int idx = tid * c + i;
        if (idx < M) {
            const int t = idx / nblk, r = idx - t * nblk;
            if (r == vb) base_lds[t] = excl;
            if (vb == 0 && r == 0) bondOff[t] = excl;
            excl += blockBondCnt[idx];
        }
    }
    if (vb == 0 && tid == 255) bondOff[NB] = chunkpre[255];
    __syncthreads();

    const int lane = tid & 63, wave = tid >> 6;
    const int e = vb * 256 + tid;
    const bool act = (e < TE);
    int sN = 0, dN = 0, bt = -1;
    if (act) {
        if (e < Ep) { sN = src[e]; dN = dst[e]; bt = bond[e]; }
        else        { sN = dst[e - Ep]; dN = src[e - Ep]; bt = bond[e - Ep]; }
        const int p = atomicAdd(&rowFill[sN], 1);
        if (p < PAD) {
            edge_col[sN * PAD + p] = dN;
            edge_eid[sN * PAD + p] = e;
            padPos[e] = sN * PAD + p;
        } else padPos[e] = -1;
    }
    int myrank = 0;
#pragma unroll
    for (int t = 0; t < NB; ++t) {
        const unsigned long long m = __ballot(bt == t);
        if (lane == 0) wcnt[wave][t] = (int)__popcll(m);
        if (bt == t) myrank = (int)__popcll(m & ((1ull << lane) - 1ull));
    }
    __syncthreads();
    if (tid < NB) {
        int sum = 0;
#pragma unroll
        for (int w = 0; w < 4; ++w) { wbase[w][tid] = sum; sum += wcnt[w][tid]; }
    }
    __syncthreads();
    if (act) bond_edges[base_lds[bt] + wbase[wave][bt] + myrank] = e;
}

// ---- MFMA grouped edge MLP: xs/h0 LDS union (32KB) -> 4 blocks/CU ----
__global__ __launch_bounds__(256) void mlp_kernel(
    const unsigned short* __restrict__ Qbf, const unsigned short* __restrict__ Kbf,
    const int* __restrict__ src, const int* __restrict__ dst, int Ep,
    const int* __restrict__ bondOff, const int* __restrict__ bond_edges,
    const int* __restrict__ padPos,
    const unsigned short* __restrict__ W0p, const unsigned short* __restrict__ W1p,
    const float* __restrict__ b0, const float* __restrict__ b1,
    const float* __restrict__ W2, const float* __restrict__ b2,
    float* __restrict__ S)
{
    const int bt = blockIdx.y;
    const int base = bondOff[bt];
    const int cnt  = bondOff[bt + 1] - base;
    const int t0 = blockIdx.x * TILE;
    if (t0 >= cnt) return;
    const int ne = min(TILE, cnt - t0);

    // union: xs = buf[0:16K) during gather+layer0; h0(wave w) = buf[w*8K : w*8K+8K) after
    __shared__ __align__(16) unsigned char buf[32768];
    __shared__ int eids[TILE];

    const int tid = threadIdx.x;
    if (tid < TILE) eids[tid] = (tid < ne) ? bond_edges[base + t0 + tid] : 0;
    __syncthreads();

    // gather x = [Q[s] | K[d]] bf16 into swizzled xs
    for (int i = tid; i < 1024; i += 256) {
        const int el = i >> 4, u = i & 15;
        uint4 v = make_uint4(0, 0, 0, 0);
        if (el < ne) {
            const int e = eids[el];
            int s, d;
            if (e < Ep) { s = src[e]; d = dst[e]; }
            else        { s = dst[e - Ep]; d = src[e - Ep]; }
            v = (u < 8) ? ((const uint4*)(Qbf + s * 64))[u]
                        : ((const uint4*)(Kbf + d * 64))[u - 8];
        }
        const int b = (el << 8) + (u << 4);
        *(uint4*)(buf + (b ^ ((el & 7) << 4))) = v;
    }
    __syncthreads();

    const int lane = tid & 63;
    const int h = tid >> 6;
    const int bh = bt * H + h;
    const int lg = lane >> 4;
    const int lr = lane & 15;

    // ---- layer 0: H0 = relu(X @ W0 + b0), K=128 ----
    f32x4 acc[4][4];
    const float* bb0 = b0 + bh * 64;
#pragma unroll
    for (int nt = 0; nt < 4; ++nt) {
        const float bv = bb0[(nt << 4) + lr];
#pragma unroll
        for (int mt = 0; mt < 4; ++mt) acc[mt][nt] = (f32x4){bv, bv, bv, bv};
    }
    const short8* W0f = (const short8*)W0p + (size_t)bh * 1024;
#pragma unroll
    for (int ks = 0; ks < 4; ++ks) {
        short8 a[4];
        const int koff = (ks << 6) + (lg << 4);
#pragma unroll
        for (int mt = 0; mt < 4; ++mt) {
            const int row = (mt << 4) + lr;
            const int b = (row << 8) + koff;
            a[mt] = *(const short8*)(buf + (b ^ ((row & 7) << 4)));
        }
        short8 bfr[4];
#pragma unroll
        for (int nt = 0; nt < 4; ++nt) bfr[nt] = W0f[(((ks << 2) + nt) << 6) + lane];
#pragma unroll
        for (int mt = 0; mt < 4; ++mt)
#pragma unroll
            for (int nt = 0; nt < 4; ++nt)
                acc[mt][nt] = __builtin_amdgcn_mfma_f32_16x16x32_bf16(a[mt], bfr[nt], acc[mt][nt], 0, 0, 0);
    }
    // all waves have consumed xs; safe to overlay H0 onto it
    __syncthreads();
    unsigned char* h0 = buf + h * 8192;
#pragma unroll
    for (int mt = 0; mt < 4; ++mt)
#pragma unroll
        for (int nt = 0; nt < 4; ++nt)
#pragma unroll
            for (int r = 0; r < 4; ++r) {
                const int row = (mt << 4) + (lg << 2) + r;
                const int col = (nt << 4) + lr;
                const int b = (row << 7) + (col << 1);
                *(unsigned short*)(h0 + (b ^ ((row & 7) << 4))) = f2bf(fmaxf(acc[mt][nt][r], 0.f));
            }

    // ---- layer 1: H1 = relu(H0 @ W1 + b1), K=64 ----
    f32x4 acc1[4][4];
    const float* bb1 = b1 + bh * 64;
#pragma unroll
    for (int nt = 0; nt < 4; ++nt) {
        const float bv = bb1[(nt << 4) + lr];
#pragma unroll
        for (int mt = 0; mt < 4; ++mt) acc1[mt][nt] = (f32x4){bv, bv, bv, bv};
    }
    const short8* W1f = (const short8*)W1p + (size_t)bh * 512;
#pragma unroll
    for (int ks = 0; ks < 2; ++ks) {
        short8 a[4];
        const int koff = (ks << 6) + (lg << 4);
#pragma unroll
        for (int mt = 0; mt < 4; ++mt) {
            const int row = (mt << 4) + lr;
            const int b = (row << 7) + koff;
            a[mt] = *(const short8*)(h0 + (b ^ ((row & 7) << 4)));
        }
        short8 bfr[4];
#pragma unroll
        for (int nt = 0; nt < 4; ++nt) bfr[nt] = W1f[(((ks << 2) + nt) << 6) + lane];
#pragma unroll
        for (int mt = 0; mt < 4; ++mt)
#pragma unroll
            for (int nt = 0; nt < 4; ++nt)
                acc1[mt][nt] = __builtin_amdgcn_mfma_f32_16x16x32_bf16(a[mt], bfr[nt], acc1[mt][nt], 0, 0, 0);
    }

    // ---- layer 2 + leaky relu ----
    const float* w2 = W2 + bh * 64;
    float w2v[4];
#pragma unroll
    for (int nt = 0; nt < 4; ++nt) w2v[nt] = w2[(nt << 4) + lr];
    float p[4][4];
#pragma unroll
    for (int mt = 0; mt < 4; ++mt)
#pragma unroll
        for (int r = 0; r < 4; ++r) {
            float s = 0.f;
#pragma unroll
            for (int nt = 0; nt < 4; ++nt) s += fmaxf(acc1[mt][nt][r], 0.f) * w2v[nt];
            p[mt][r] = s;
        }
#pragma unroll
    for (int off = 1; off <= 8; off <<= 1)
#pragma unroll
        for (int mt = 0; mt < 4; ++mt)
#pragma unroll
            for (int r = 0; r < 4; ++r) p[mt][r] += __shfl_xor(p[mt][r], off, 64);
    const int e_w = ((lr >> 2) << 4) + (lg << 2) + (lr & 3);
    float sc = p[lr >> 2][lr & 3] + b2[bh];
    sc = sc > 0.f ? sc : NEG_SLOPE * sc;
    if (e_w < ne) {
        const int pp = padPos[eids[e_w]];
        if (pp >= 0) S[(size_t)pp * H + h] = sc;
    }
}

// ---- agg: padded rows; softmax per head-wave; PV split across waves by edge; fused projection ----
__global__ __launch_bounds__(256) void agg_kernel(
    const float* __restrict__ V, const float* __restrict__ S,
    const int* __restrict__ rowFill,
    const int* __restrict__ edge_col, const int* __restrict__ edge_eid,
    const float* __restrict__ Pw, const float* __restrict__ Pb, float* __restrict__ out)
{
    const int row = blockIdx.x;
    const int tid = threadIdx.x;
    const int lane = tid & 63;
    const int wv = tid >> 6;
    const int beg = row * PAD;
    int deg = rowFill[row];
    if (deg > PAD) deg = PAD;

    __shared__ int tcol[PAD], teid[PAD], scol[PAD], spos[PAD], win[PAD];
    __shared__ float wgt[4][PAD];
    __shared__ float sdn[4];
    __shared__ float partv[4][4][64];
    __shared__ float rr[256];
    __shared__ float part2[4][64];

    for (int a = tid; a < deg; a += 256) { tcol[a] = edge_col[beg + a]; teid[a] = edge_eid[beg + a]; }
    __syncthreads();
    for (int a = tid; a < deg; a += 256) {
        const int e = teid[a];
        int r = 0;
        for (int b = 0; b < deg; ++b) r += (teid[b] < e);
        scol[r] = tcol[a];
        spos[r] = a;
    }
    __syncthreads();
    for (int a = tid; a < deg; a += 256) {
        const int c = scol[a];
        int wn = 1;
        for (int b = a + 1; b < deg; ++b) if (scol[b] == c) { wn = 0; break; }
        win[a] = wn;
    }
    __syncthreads();

    // softmax: wave wv handles head wv
    float m = -1e30f;
    for (int a = lane; a < deg; a += 64)
        if (win[a]) m = fmaxf(m, S[(size_t)(beg + spos[a]) * H + wv]);
#pragma unroll
    for (int off = 32; off; off >>= 1) m = fmaxf(m, __shfl_xor(m, off, 64));

    float dn = 0.f;
    for (int a = lane; a < deg; a += 64) {
        const float wvv = win[a] ? __expf(S[(size_t)(beg + spos[a]) * H + wv] - m) : 0.f;
        wgt[wv][a] = wvv;
        dn += wvv;
    }
#pragma unroll
    for (int off = 32; off; off >>= 1) dn += __shfl_xor(dn, off, 64);
    if (lane == 0) sdn[wv] = dn;
    __syncthreads();

    // PV: wave wv covers edges a = wv, wv+4, ...; each V row loaded once, used by all 4 heads
    float pv0 = 0.f, pv1 = 0.f, pv2 = 0.f, pv3 = 0.f;
    for (int a = wv; a < deg; a += 4) {
        const float vr = V[(size_t)scol[a] * D + lane];
        pv0 += wgt[0][a] * vr;
        pv1 += wgt[1][a] * vr;
        pv2 += wgt[2][a] * vr;
        pv3 += wgt[3][a] * vr;
    }
    partv[wv][0][lane] = pv0;
    partv[wv][1][lane] = pv1;
    partv[wv][2][lane] = pv2;
    partv[wv][3][lane] = pv3;
    __syncthreads();

    // reduce partials: wave wv owns head wv
    rr[wv * 64 + lane] = (partv[0][wv][lane] + partv[1][wv][lane]
                        + partv[2][wv][lane] + partv[3][wv][lane]) / sdn[wv];
    __syncthreads();

    // fused projection
    {
        float sps = 0.f;
#pragma unroll 8
        for (int k = 0; k < 64; ++k) sps += rr[wv * 64 + k] * Pw[(wv * 64 + k) * D + lane];
        part2[wv][lane] = sps;
    }
    __syncthreads();
    if (tid < 64)
        out[(size_t)row * D + tid] = part2[0][tid] + part2[1][tid] + part2[2][tid] + part2[3][tid] + Pb[tid];
}

extern "C" void kernel_launch(void* const* d_in, const int* in_sizes, int n_in,
                              void* d_out, int out_size, void* d_ws, size_t ws_size,
                              hipStream_t stream)
{
    const float* emb = (const float*)d_in[0];
    const float* Qw  = (const float*)d_in[1];
    const float* Qb  = (const float*)d_in[2];
    const float* Kw  = (const float*)d_in[3];
    const float* Kb  = (const float*)d_in[4];
    const float* Vw  = (const float*)d_in[5];
    const float* Vb  = (const float*)d_in[6];
    const float* W0  = (const float*)d_in[7];
    const float* b0  = (const float*)d_in[8];
    const float* W1  = (const float*)d_in[9];
    const float* b1  = (const float*)d_in[10];
    const float* W2  = (const float*)d_in[11];
    const float* b2  = (const float*)d_in[12];
    const float* Pw  = (const float*)d_in[13];
    const float* Pb  = (const float*)d_in[14];
    const int* src   = (const int*)d_in[15];
    const int* dst   = (const int*)d_in[16];
    const int* bond  = (const int*)d_in[17];

    const int N  = in_sizes[0] / D;
    const int Ep = in_sizes[15];
    const int TE = 2 * Ep;
    const int nblk = (TE + 255) / 256;
    const int nq = (N + 3) / 4;

    char* w = (char*)d_ws;
    auto alloc = [&](size_t bytes) -> void* {
        void* p = (void*)w;
        w += ((bytes + 255) / 256) * 256;
        return p;
    };
    unsigned short* Qbf = (unsigned short*)alloc((size_t)N * D * 2);
    unsigned short* Kbf = (unsigned short*)alloc((size_t)N * D * 2);
    float* V        = (float*)alloc((size_t)N * D * 4);
    unsigned short* W0p = (unsigned short*)alloc((size_t)131072 * 2);
    unsigned short* W1p = (unsigned short*)alloc((size_t)65536 * 2);
    float* S        = (float*)alloc((size_t)N * PAD * H * 4);
    int* edge_col   = (int*)alloc((size_t)N * PAD * 4);
    int* edge_eid   = (int*)alloc((size_t)N * PAD * 4);
    int* bond_edges = (int*)alloc((size_t)TE * 4);
    int* padPos     = (int*)alloc((size_t)TE * 4);
    int* blockBondCnt = (int*)alloc((size_t)NB * nblk * 4);
    int* bondOff    = (int*)alloc((size_t)(NB + 1) * 4);
    int* rowFill    = (int*)alloc((size_t)N * 4);
    if ((size_t)(w - (char*)d_ws) > ws_size) return;

    prep_kernel<<<nq + 512 + nblk, 256, 0, stream>>>(
        emb, Qw, Qb, Kw, Kb, Vw, Vb, Qbf, Kbf, V, W0, W1, W0p, W1p,
        bond, Ep, TE, rowFill, blockBondCnt, nblk, N, nq);
    scatter_kernel<<<nblk, 256, 0, stream>>>(
        src, dst, bond, Ep, TE, nblk, blockBondCnt, rowFill,
        edge_col, edge_eid, padPos, bond_edges, bondOff);
    dim3 mgrid((TE + TILE - 1) / TILE, NB);
    mlp_kernel<<<mgrid, 256, 0, stream>>>(
        Qbf, Kbf, src, dst, Ep, bondOff, bond_edges, padPos,
        W0p, W1p, b0, b1, W2, b2, S);
    agg_kernel<<<N, 256, 0, stream>>>(
        V, S, rowFill, edge_col, edge_eid, Pw, Pb, (float*)d_out);
}

// Round 9
// 76.438 us; speedup vs baseline: 5.6019x; 1.0193x over previous
//
#include <hip/hip_runtime.h>
#include <hip/hip_bf16.h>
#include <math.h>

#define D 64
#define H 4
#define NB 4
#define TILE 64
#define PAD 128
#define NEG_SLOPE 0.2f

typedef __attribute__((ext_vector_type(8))) short short8;
typedef __attribute__((ext_vector_type(4))) float f32x4;

__device__ __forceinline__ unsigned short f2bf(float f) {
    union { float f; unsigned int u; } c; c.f = f;
    const unsigned int u = c.u;
    return (unsigned short)((u + 0x7fffu + ((u >> 16) & 1u)) >> 16);
}

// ---- prep: [0,nq8) LDS-staged QKV (8 nodes/block) + zero rowFill ;
//            [nq8,nq8+512) weight prepack ; [nq8+512,..) bond histogram ----
__global__ __launch_bounds__(256) void prep_kernel(
    const float* __restrict__ emb,
    const float* __restrict__ Qw, const float* __restrict__ Qb,
    const float* __restrict__ Kw, const float* __restrict__ Kb,
    const float* __restrict__ Vw, const float* __restrict__ Vb,
    unsigned short* __restrict__ Qbf, unsigned short* __restrict__ Kbf,
    float* __restrict__ V,
    const float* __restrict__ W0, const float* __restrict__ W1,
    unsigned short* __restrict__ W0p, unsigned short* __restrict__ W1p,
    const int* __restrict__ bond, int Ep, int TE,
    int* __restrict__ rowFill, int* __restrict__ blockBondCnt, int nblk,
    int N, int nq8)
{
    // segA layout: wq[0:16K) wk[16K:32K) wv[32K:48K) et[48K:50K)
    __shared__ __align__(16) unsigned char pbuf[51200];
    const int tid = threadIdx.x;
    const int bid = blockIdx.x;
    if (bid < nq8) {
        float* wq = (float*)pbuf;
        float* wk = (float*)(pbuf + 16384);
        float* wv = (float*)(pbuf + 32768);
        float* et = (float*)(pbuf + 49152);   // 8 x 64
        const int base_n = bid * 8;
        if (tid < 8 && base_n + tid < N) rowFill[base_n + tid] = 0;
        {
            const float4* q4 = (const float4*)Qw;
            const float4* k4 = (const float4*)Kw;
            const float4* v4 = (const float4*)Vw;
            float4* wq4 = (float4*)wq;
            float4* wk4 = (float4*)wk;
            float4* wv4 = (float4*)wv;
            for (int i = tid; i < 1024; i += 256) {
                wq4[i] = q4[i];
                wk4[i] = k4[i];
                wv4[i] = v4[i];
            }
        }
        for (int i = tid; i < 512; i += 256) {
            const int n = base_n + (i >> 6);
            et[i] = (n < N) ? emb[n * D + (i & 63)] : 0.f;
        }
        __syncthreads();
        const int lane = tid & 63, wave = tid >> 6;
        const int d = lane;
#pragma unroll
        for (int r = 0; r < 2; ++r) {
            const int li = r * 4 + wave;
            const int n = base_n + li;
            if (n < N) {
                float aq = Qb[d], ak = Kb[d], av = Vb[d];
                const float* er = et + li * 64;
#pragma unroll 8
                for (int k = 0; k < D; ++k) {
                    const float x = er[k];
                    aq += x * wq[k * D + d];
                    ak += x * wk[k * D + d];
                    av += x * wv[k * D + d];
                }
                Qbf[n * D + d] = f2bf(aq);
                Kbf[n * D + d] = f2bf(ak);
                V[n * D + d] = av;
            }
        }
    } else if (bid < nq8 + 512) {
        const int idx = (bid - nq8) * 256 + tid;   // < 131072
        {
            const int j = idx & 7, ln = (idx >> 3) & 63, nt = (idx >> 9) & 3;
            const int ks = (idx >> 11) & 3, bh = idx >> 13;
            const int k = ks * 32 + ((ln >> 4) << 3) + j;
            const int nn = (nt << 4) + (ln & 15);
            W0p[idx] = f2bf(W0[((size_t)bh * 128 + k) * 64 + nn]);
        }
        if (idx < 65536) {
            const int j = idx & 7, ln = (idx >> 3) & 63, nt = (idx >> 9) & 3;
            const int ks = (idx >> 11) & 1, bh = idx >> 12;
            const int k = ks * 32 + ((ln >> 4) << 3) + j;
            const int nn = (nt << 4) + (ln & 15);
            W1p[idx] = f2bf(W1[((size_t)bh * 64 + k) * 64 + nn]);
        }
    } else {
        int* wcnt = (int*)pbuf;   // [4][NB]
        const int vb = bid - nq8 - 512;
        const int e = vb * 256 + tid;
        const int lane = tid & 63, wave = tid >> 6;
        int bt = -1;
        if (e < TE) bt = (e < Ep) ? bond[e] : bond[e - Ep];
#pragma unroll
        for (int t = 0; t < NB; ++t) {
            const unsigned long long m = __ballot(bt == t);
            if (lane == 0) wcnt[wave * NB + t] = (int)__popcll(m);
        }
        __syncthreads();
        if (tid < NB) {
            int s = 0;
#pragma unroll
            for (int w = 0; w < 4; ++w) s += wcnt[w * NB + tid];
            blockBondCnt[tid * nblk + vb] = s;
        }
    }
}

// ---- scatter: in-block scan of blockBondCnt -> bases; padded row lists + bond buckets ----
__global__ __launch_bounds__(256) void scatter_kernel(
    const int* __restrict__ src, const int* __restrict__ dst,
    const int* __restrict__ bond, int Ep, int TE, int nblk,
    const int* __restrict__ blockBondCnt, int* __restrict__ rowFill,
    int* __restrict__ edge_col, int* __restrict__ edge_eid,
    int* __restrict__ padPos, int* __restrict__ bond_edges, int* __restrict__ bondOff)
{
    __shared__ int chunkpre[256];
    __shared__ int base_lds[NB];
    __shared__ int wcnt[4][NB], wbase[4][NB];
    const int tid = threadIdx.x;
    const int vb = blockIdx.x;
    const int M = NB * nblk;
    const int c = (M + 255) >> 8;

    int s = 0;
    for (int i = 0; i < c; ++i) { const int idx = tid * c + i; if (idx < M) s += blockBondCnt[idx]; }
    chunkpre[tid] = s;
    __syncthreads();
    int val = s;
    for (int off = 1; off < 256; off <<= 1) {
        const int o = (tid >= off) ? chunkpre[tid - off] : 0;
        __syncthreads();
        val += o;
        chunkpre[tid] = val;
        __syncthreads();
    }
    int excl = val - s;
    for (int i = 0; i < c; ++i) {
        const int idx = tid * c + i;
        if (idx < M) {
            const int t = idx / nblk, r = idx - t * nblk;
            if (r == vb) base_lds[t] = excl;
            if (vb == 0 && r == 0) bondOff[t] = excl;
            excl += blockBondCnt[idx];
        }
    }
    if (vb == 0 && tid == 255) bondOff[NB] = chunkpre[255];
    __syncthreads();

    const int lane = tid & 63, wave = tid >> 6;
    const int e = vb * 256 + tid;
    const bool act = (e < TE);
    int sN = 0, dN = 0, bt = -1;
    if (act) {
        if (e < Ep) { sN = src[e]; dN = dst[e]; bt = bond[e]; }
        else        { sN = dst[e - Ep]; dN = src[e - Ep]; bt = bond[e - Ep]; }
        const int p = atomicAdd(&rowFill[sN], 1);
        if (p < PAD) {
            edge_col[sN * PAD + p] = dN;
            edge_eid[sN * PAD + p] = e;
            padPos[e] = sN * PAD + p;
        } else padPos[e] = -1;
    }
    int myrank = 0;
#pragma unroll
    for (int t = 0; t < NB; ++t) {
        const unsigned long long m = __ballot(bt == t);
        if (lane == 0) wcnt[wave][t] = (int)__popcll(m);
        if (bt == t) myrank = (int)__popcll(m & ((1ull << lane) - 1ull));
    }
    __syncthreads();
    if (tid < NB) {
        int sum = 0;
#pragma unroll
        for (int w = 0; w < 4; ++w) { wbase[w][tid] = sum; sum += wcnt[w][tid]; }
    }
    __syncthreads();
    if (act) bond_edges[base_lds[bt] + wbase[wave][bt] + myrank] = e;
}

// ---- MFMA grouped edge MLP: xs/h0 LDS union (32KB); padPos prefetched under layer-0 ----
__global__ __launch_bounds__(256) void mlp_kernel(
    const unsigned short* __restrict__ Qbf, const unsigned short* __restrict__ Kbf,
    const int* __restrict__ src, const int* __restrict__ dst, int Ep,
    const int* __restrict__ bondOff, const int* __restrict__ bond_edges,
    const int* __restrict__ padPos,
    const unsigned short* __restrict__ W0p, const unsigned short* __restrict__ W1p,
    const float* __restrict__ b0, const float* __restrict__ b1,
    const float* __restrict__ W2, const float* __restrict__ b2,
    float* __restrict__ S)
{
    const int bt = blockIdx.y;
    const int base = bondOff[bt];
    const int cnt  = bondOff[bt + 1] - base;
    const int t0 = blockIdx.x * TILE;
    if (t0 >= cnt) return;
    const int ne = min(TILE, cnt - t0);

    // union: xs = buf[0:16K) during gather+layer0; h0(wave w) = buf[w*8K : w*8K+8K) after
    __shared__ __align__(16) unsigned char buf[32768];
    __shared__ int eids[TILE];

    const int tid = threadIdx.x;
    if (tid < TILE) eids[tid] = (tid < ne) ? bond_edges[base + t0 + tid] : 0;
    __syncthreads();

    // gather x = [Q[s] | K[d]] bf16 into swizzled xs
    for (int i = tid; i < 1024; i += 256) {
        const int el = i >> 4, u = i & 15;
        uint4 v = make_uint4(0, 0, 0, 0);
        if (el < ne) {
            const int e = eids[el];
            int s, d;
            if (e < Ep) { s = src[e]; d = dst[e]; }
            else        { s = dst[e - Ep]; d = src[e - Ep]; }
            v = (u < 8) ? ((const uint4*)(Qbf + s * 64))[u]
                        : ((const uint4*)(Kbf + d * 64))[u - 8];
        }
        const int b = (el << 8) + (u << 4);
        *(uint4*)(buf + (b ^ ((el & 7) << 4))) = v;
    }

    const int lane = tid & 63;
    const int h = tid >> 6;
    const int bh = bt * H + h;
    const int lg = lane >> 4;
    const int lr = lane & 15;

    // prefetch the epilogue's padPos (independent of LDS) so its latency hides under layer 0
    const int e_w = ((lr >> 2) << 4) + (lg << 2) + (lr & 3);
    const int pp = (e_w < ne) ? padPos[eids[e_w]] : -1;
    __syncthreads();

    // ---- layer 0: H0 = relu(X @ W0 + b0), K=128 ----
    f32x4 acc[4][4];
    const float* bb0 = b0 + bh * 64;
#pragma unroll
    for (int nt = 0; nt < 4; ++nt) {
        const float bv = bb0[(nt << 4) + lr];
#pragma unroll
        for (int mt = 0; mt < 4; ++mt) acc[mt][nt] = (f32x4){bv, bv, bv, bv};
    }
    const short8* W0f = (const short8*)W0p + (size_t)bh * 1024;
#pragma unroll
    for (int ks = 0; ks < 4; ++ks) {
        short8 a[4];
        const int koff = (ks << 6) + (lg << 4);
#pragma unroll
        for (int mt = 0; mt < 4; ++mt) {
            const int row = (mt << 4) + lr;
            const int b = (row << 8) + koff;
            a[mt] = *(const short8*)(buf + (b ^ ((row & 7) << 4)));
        }
        short8 bfr[4];
#pragma unroll
        for (int nt = 0; nt < 4; ++nt) bfr[nt] = W0f[(((ks << 2) + nt) << 6) + lane];
#pragma unroll
        for (int mt = 0; mt < 4; ++mt)
#pragma unroll
            for (int nt = 0; nt < 4; ++nt)
                acc[mt][nt] = __builtin_amdgcn_mfma_f32_16x16x32_bf16(a[mt], bfr[nt], acc[mt][nt], 0, 0, 0);
    }
    // all waves have consumed xs; safe to overlay H0 onto it
    __syncthreads();
    unsigned char* h0 = buf + h * 8192;
#pragma unroll
    for (int mt = 0; mt < 4; ++mt)
#pragma unroll
        for (int nt = 0; nt < 4; ++nt)
#pragma unroll
            for (int r = 0; r < 4; ++r) {
                const int row = (mt << 4) + (lg << 2) + r;
                const int col = (nt << 4) + lr;
                const int b = (row << 7) + (col << 1);
                *(unsigned short*)(h0 + (b ^ ((row & 7) << 4))) = f2bf(fmaxf(acc[mt][nt][r], 0.f));
            }

    // ---- layer 1: H1 = relu(H0 @ W1 + b1), K=64 ----
    f32x4 acc1[4][4];
    const float* bb1 = b1 + bh * 64;
#pragma unroll
    for (int nt = 0; nt < 4; ++nt) {
        const float bv = bb1[(nt << 4) + lr];
#pragma unroll
        for (int mt = 0; mt < 4; ++mt) acc1[mt][nt] = (f32x4){bv, bv, bv, bv};
    }
    const short8* W1f = (const short8*)W1p + (size_t)bh * 512;
#pragma unroll
    for (int ks = 0; ks < 2; ++ks) {
        short8 a[4];
        const int koff = (ks << 6) + (lg << 4);
#pragma unroll
        for (int mt = 0; mt < 4; ++mt) {
            const int row = (mt << 4) + lr;
            const int b = (row << 7) + koff;
            a[mt] = *(const short8*)(h0 + (b ^ ((row & 7) << 4)));
        }
        short8 bfr[4];
#pragma unroll
        for (int nt = 0; nt < 4; ++nt) bfr[nt] = W1f[(((ks << 2) + nt) << 6) + lane];
#pragma unroll
        for (int mt = 0; mt < 4; ++mt)
#pragma unroll
            for (int nt = 0; nt < 4; ++nt)
                acc1[mt][nt] = __builtin_amdgcn_mfma_f32_16x16x32_bf16(a[mt], bfr[nt], acc1[mt][nt], 0, 0, 0);
    }

    // ---- layer 2 + leaky relu ----
    const float* w2 = W2 + bh * 64;
    float w2v[4];
#pragma unroll
    for (int nt = 0; nt < 4; ++nt) w2v[nt] = w2[(nt << 4) + lr];
    float p[4][4];
#pragma unroll
    for (int mt = 0; mt < 4; ++mt)
#pragma unroll
        for (int r = 0; r < 4; ++r) {
            float s = 0.f;
#pragma unroll
            for (int nt = 0; nt < 4; ++nt) s += fmaxf(acc1[mt][nt][r], 0.f) * w2v[nt];
            p[mt][r] = s;
        }
#pragma unroll
    for (int off = 1; off <= 8; off <<= 1)
#pragma unroll
        for (int mt = 0; mt < 4; ++mt)
#pragma unroll
            for (int r = 0; r < 4; ++r) p[mt][r] += __shfl_xor(p[mt][r], off, 64);
    float sc = p[lr >> 2][lr & 3] + b2[bh];
    sc = sc > 0.f ? sc : NEG_SLOPE * sc;
    if (e_w < ne && pp >= 0) S[(size_t)pp * H + h] = sc;
}

// ---- agg: padded rows; softmax per head-wave; PV split across waves by edge; fused projection ----
__global__ __launch_bounds__(256) void agg_kernel(
    const float* __restrict__ V, const float* __restrict__ S,
    const int* __restrict__ rowFill,
    const int* __restrict__ edge_col, const int* __restrict__ edge_eid,
    const float* __restrict__ Pw, const float* __restrict__ Pb, float* __restrict__ out)
{
    const int row = blockIdx.x;
    const int tid = threadIdx.x;
    const int lane = tid & 63;
    const int wv = tid >> 6;
    const int beg = row * PAD;
    int deg = rowFill[row];
    if (deg > PAD) deg = PAD;

    __shared__ int tcol[PAD], teid[PAD], scol[PAD], spos[PAD], win[PAD];
    __shared__ float wgt[4][PAD];
    __shared__ float sdn[4];
    __shared__ float partv[4][4][64];
    __shared__ float rr[256];
    __shared__ float part2[4][64];

    for (int a = tid; a < deg; a += 256) { tcol[a] = edge_col[beg + a]; teid[a] = edge_eid[beg + a]; }
    __syncthreads();
    for (int a = tid; a < deg; a += 256) {
        const int e = teid[a];
        int r = 0;
        for (int b = 0; b < deg; ++b) r += (teid[b] < e);
        scol[r] = tcol[a];
        spos[r] = a;
    }
    __syncthreads();
    for (int a = tid; a < deg; a += 256) {
        const int c = scol[a];
        int wn = 1;
        for (int b = a + 1; b < deg; ++b) if (scol[b] == c) { wn = 0; break; }
        win[a] = wn;
    }
    __syncthreads();

    // softmax: wave wv handles head wv
    float m = -1e30f;
    for (int a = lane; a < deg; a += 64)
        if (win[a]) m = fmaxf(m, S[(size_t)(beg + spos[a]) * H + wv]);
#pragma unroll
    for (int off = 32; off; off >>= 1) m = fmaxf(m, __shfl_xor(m, off, 64));

    float dn = 0.f;
    for (int a = lane; a < deg; a += 64) {
        const float wvv = win[a] ? __expf(S[(size_t)(beg + spos[a]) * H + wv] - m) : 0.f;
        wgt[wv][a] = wvv;
        dn += wvv;
    }
#pragma unroll
    for (int off = 32; off; off >>= 1) dn += __shfl_xor(dn, off, 64);
    if (lane == 0) sdn[wv] = dn;
    __syncthreads();

    // PV: wave wv covers edges a = wv, wv+4, ...; each V row loaded once, used by all 4 heads
    float pv0 = 0.f, pv1 = 0.f, pv2 = 0.f, pv3 = 0.f;
    for (int a = wv; a < deg; a += 4) {
        const float vr = V[(size_t)scol[a] * D + lane];
        pv0 += wgt[0][a] * vr;
        pv1 += wgt[1][a] * vr;
        pv2 += wgt[2][a] * vr;
        pv3 += wgt[3][a] * vr;
    }
    partv[wv][0][lane] = pv0;
    partv[wv][1][lane] = pv1;
    partv[wv][2][lane] = pv2;
    partv[wv][3][lane] = pv3;
    __syncthreads();

    // reduce partials: wave wv owns head wv
    rr[wv * 64 + lane] = (partv[0][wv][lane] + partv[1][wv][lane]
                        + partv[2][wv][lane] + partv[3][wv][lane]) / sdn[wv];
    __syncthreads();

    // fused projection
    {
        float sps = 0.f;
#pragma unroll 8
        for (int k = 0; k < 64; ++k) sps += rr[wv * 64 + k] * Pw[(wv * 64 + k) * D + lane];
        part2[wv][lane] = sps;
    }
    __syncthreads();
    if (tid < 64)
        out[(size_t)row * D + tid] = part2[0][tid] + part2[1][tid] + part2[2][tid] + part2[3][tid] + Pb[tid];
}

extern "C" void kernel_launch(void* const* d_in, const int* in_sizes, int n_in,
                              void* d_out, int out_size, void* d_ws, size_t ws_size,
                              hipStream_t stream)
{
    const float* emb = (const float*)d_in[0];
    const float* Qw  = (const float*)d_in[1];
    const float* Qb  = (const float*)d_in[2];
    const float* Kw  = (const float*)d_in[3];
    const float* Kb  = (const float*)d_in[4];
    const float* Vw  = (const float*)d_in[5];
    const float* Vb  = (const float*)d_in[6];
    const float* W0  = (const float*)d_in[7];
    const float* b0  = (const float*)d_in[8];
    const float* W1  = (const float*)d_in[9];
    const float* b1  = (const float*)d_in[10];
    const float* W2  = (const float*)d_in[11];
    const float* b2  = (const float*)d_in[12];
    const float* Pw  = (const float*)d_in[13];
    const float* Pb  = (const float*)d_in[14];
    const int* src   = (const int*)d_in[15];
    const int* dst   = (const int*)d_in[16];
    const int* bond  = (const int*)d_in[17];

    const int N  = in_sizes[0] / D;
    const int Ep = in_sizes[15];
    const int TE = 2 * Ep;
    const int nblk = (TE + 255) / 256;
    const int nq8 = (N + 7) / 8;

    char* w = (char*)d_ws;
    auto alloc = [&](size_t bytes) -> void* {
        void* p = (void*)w;
        w += ((bytes + 255) / 256) * 256;
        return p;
    };
    unsigned short* Qbf = (unsigned short*)alloc((size_t)N * D * 2);
    unsigned short* Kbf = (unsigned short*)alloc((size_t)N * D * 2);
    float* V        = (float*)alloc((size_t)N * D * 4);
    unsigned short* W0p = (unsigned short*)alloc((size_t)131072 * 2);
    unsigned short* W1p = (unsigned short*)alloc((size_t)65536 * 2);
    float* S        = (float*)alloc((size_t)N * PAD * H * 4);
    int* edge_col   = (int*)alloc((size_t)N * PAD * 4);
    int* edge_eid   = (int*)alloc((size_t)N * PAD * 4);
    int* bond_edges = (int*)alloc((size_t)TE * 4);
    int* padPos     = (int*)alloc((size_t)TE * 4);
    int* blockBondCnt = (int*)alloc((size_t)NB * nblk * 4);
    int* bondOff    = (int*)alloc((size_t)(NB + 1) * 4);
    int* rowFill    = (int*)alloc((size_t)N * 4);
    if ((size_t)(w - (char*)d_ws) > ws_size) return;

    prep_kernel<<<nq8 + 512 + nblk, 256, 0, stream>>>(
        emb, Qw, Qb, Kw, Kb, Vw, Vb, Qbf, Kbf, V, W0, W1, W0p, W1p,
        bond, Ep, TE, rowFill, blockBondCnt, nblk, N, nq8);
    scatter_kernel<<<nblk, 256, 0, stream>>>(
        src, dst, bond, Ep, TE, nblk, blockBondCnt, rowFill,
        edge_col, edge_eid, padPos, bond_edges, bondOff);
    dim3 mgrid((TE + TILE - 1) / TILE, NB);
    mlp_kernel<<<mgrid, 256, 0, stream>>>(
        Qbf, Kbf, src, dst, Ep, bondOff, bond_edges, padPos,
        W0p, W1p, b0, b1, W2, b2, S);
    agg_kernel<<<N, 256, 0, stream>>>(
        V, S, rowFill, edge_col, edge_eid, Pw, Pb, (float*)d_out);
}

// Round 10
// 76.069 us; speedup vs baseline: 5.6290x; 1.0048x over previous
//
#include <hip/hip_runtime.h>
#include <hip/hip_bf16.h>
#include <math.h>

#define D 64
#define H 4
#define NB 4
#define TILE 64
#define PAD 128
#define NEG_SLOPE 0.2f

typedef __attribute__((ext_vector_type(8))) short short8;
typedef __attribute__((ext_vector_type(4))) float f32x4;

__device__ __forceinline__ unsigned short f2bf(float f) {
    union { float f; unsigned int u; } c; c.f = f;
    const unsigned int u = c.u;
    return (unsigned short)((u + 0x7fffu + ((u >> 16) & 1u)) >> 16);
}

// ---- prep: [0,nq8) LDS-staged QKV (8 nodes/block) + zero rowFill ;
//            [nq8,nq8+128) weight prepack (dense) ; [nq8+128,..) bond histogram (4 chunks/block) ----
__global__ __launch_bounds__(256) void prep_kernel(
    const float* __restrict__ emb,
    const float* __restrict__ Qw, const float* __restrict__ Qb,
    const float* __restrict__ Kw, const float* __restrict__ Kb,
    const float* __restrict__ Vw, const float* __restrict__ Vb,
    unsigned short* __restrict__ Qbf, unsigned short* __restrict__ Kbf,
    float* __restrict__ V,
    const float* __restrict__ W0, const float* __restrict__ W1,
    unsigned short* __restrict__ W0p, unsigned short* __restrict__ W1p,
    const int* __restrict__ bond, int Ep, int TE,
    int* __restrict__ rowFill, int* __restrict__ blockBondCnt, int nblk,
    int N, int nq8)
{
    // segA layout: wq[0:16K) wk[16K:32K) wv[32K:48K) et[48K:50K)
    __shared__ __align__(16) unsigned char pbuf[51200];
    const int tid = threadIdx.x;
    const int bid = blockIdx.x;
    if (bid < nq8) {
        float* wq = (float*)pbuf;
        float* wk = (float*)(pbuf + 16384);
        float* wv = (float*)(pbuf + 32768);
        float* et = (float*)(pbuf + 49152);   // 8 x 64
        const int base_n = bid * 8;
        if (tid < 8 && base_n + tid < N) rowFill[base_n + tid] = 0;
        {
            const float4* q4 = (const float4*)Qw;
            const float4* k4 = (const float4*)Kw;
            const float4* v4 = (const float4*)Vw;
            float4* wq4 = (float4*)wq;
            float4* wk4 = (float4*)wk;
            float4* wv4 = (float4*)wv;
            for (int i = tid; i < 1024; i += 256) {
                wq4[i] = q4[i];
                wk4[i] = k4[i];
                wv4[i] = v4[i];
            }
        }
        for (int i = tid; i < 512; i += 256) {
            const int n = base_n + (i >> 6);
            et[i] = (n < N) ? emb[n * D + (i & 63)] : 0.f;
        }
        __syncthreads();
        const int lane = tid & 63, wave = tid >> 6;
        const int d = lane;
#pragma unroll
        for (int r = 0; r < 2; ++r) {
            const int li = r * 4 + wave;
            const int n = base_n + li;
            if (n < N) {
                float aq = Qb[d], ak = Kb[d], av = Vb[d];
                const float* er = et + li * 64;
#pragma unroll 8
                for (int k = 0; k < D; ++k) {
                    const float x = er[k];
                    aq += x * wq[k * D + d];
                    ak += x * wk[k * D + d];
                    av += x * wv[k * D + d];
                }
                Qbf[n * D + d] = f2bf(aq);
                Kbf[n * D + d] = f2bf(ak);
                V[n * D + d] = av;
            }
        }
    } else if (bid < nq8 + 128) {
        const int base = (bid - nq8) * 1024;
#pragma unroll
        for (int kk = 0; kk < 4; ++kk) {
            const int idx = base + kk * 256 + tid;   // < 131072
            const int j = idx & 7, ln = (idx >> 3) & 63, nt = (idx >> 9) & 3;
            const int ks = (idx >> 11) & 3, bh = idx >> 13;
            const int k = ks * 32 + ((ln >> 4) << 3) + j;
            const int nn = (nt << 4) + (ln & 15);
            W0p[idx] = f2bf(W0[((size_t)bh * 128 + k) * 64 + nn]);
        }
        const int base1 = (bid - nq8) * 512;
#pragma unroll
        for (int kk = 0; kk < 2; ++kk) {
            const int idx = base1 + kk * 256 + tid;  // < 65536
            const int j = idx & 7, ln = (idx >> 3) & 63, nt = (idx >> 9) & 3;
            const int ks = (idx >> 11) & 1, bh = idx >> 12;
            const int k = ks * 32 + ((ln >> 4) << 3) + j;
            const int nn = (nt << 4) + (ln & 15);
            W1p[idx] = f2bf(W1[((size_t)bh * 64 + k) * 64 + nn]);
        }
    } else {
        int* wcnt = (int*)pbuf;   // [4][NB]
        const int vb4 = bid - nq8 - 128;
        const int lane = tid & 63, wave = tid >> 6;
#pragma unroll
        for (int j = 0; j < 4; ++j) {
            const int vb = vb4 * 4 + j;
            if (vb >= nblk) break;
            const int e = vb * 256 + tid;
            int bt = -1;
            if (e < TE) bt = (e < Ep) ? bond[e] : bond[e - Ep];
#pragma unroll
            for (int t = 0; t < NB; ++t) {
                const unsigned long long m = __ballot(bt == t);
                if (lane == 0) wcnt[wave * NB + t] = (int)__popcll(m);
            }
            __syncthreads();
            if (tid < NB) {
                int s = 0;
#pragma unroll
                for (int w = 0; w < 4; ++w) s += wcnt[w * NB + tid];
                blockBondCnt[tid * nblk + vb] = s;
            }
            __syncthreads();
        }
    }
}

// ---- scatter: in-block scan of blockBondCnt -> bases; padded row lists + bond buckets;
//      block 0 also emits the exact tile list for mlp ----
__global__ __launch_bounds__(256) void scatter_kernel(
    const int* __restrict__ src, const int* __restrict__ dst,
    const int* __restrict__ bond, int Ep, int TE, int nblk,
    const int* __restrict__ blockBondCnt, int* __restrict__ rowFill,
    int* __restrict__ edge_col, int* __restrict__ edge_eid,
    int* __restrict__ padPos, int* __restrict__ bond_edges, int* __restrict__ bondOff,
    int* __restrict__ tileBt, int* __restrict__ tileT0, int* __restrict__ ntiles)
{
    __shared__ int chunkpre[256];
    __shared__ int base_lds[NB];
    __shared__ int wcnt[4][NB], wbase[4][NB];
    __shared__ int tpre[NB + 1];
    const int tid = threadIdx.x;
    const int vb = blockIdx.x;
    const int M = NB * nblk;
    const int c = (M + 255) >> 8;

    int s = 0;
    for (int i = 0; i < c; ++i) { const int idx = tid * c + i; if (idx < M) s += blockBondCnt[idx]; }
    chunkpre[tid] = s;
    __syncthreads();
    int val = s;
    for (int off = 1; off < 256; off <<= 1) {
        const int o = (tid >= off) ? chunkpre[tid - off] : 0;
        __syncthreads();
        val += o;
        chunkpre[tid] = val;
        __syncthreads();
    }
    int excl = val - s;
    for (int i = 0; i < c; ++i) {
        const int idx = tid * c + i;
        if (idx < M) {
            const int t = idx / nblk, r = idx - t * nblk;
            if (r == vb) base_lds[t] = excl;
            if (vb == 0 && r == 0) bondOff[t] = excl;
            excl += blockBondCnt[idx];
        }
    }
    if (vb == 0 && tid == 255) bondOff[NB] = chunkpre[255];
    __syncthreads();

    const int lane = tid & 63, wave = tid >> 6;
    const int e = vb * 256 + tid;
    const bool act = (e < TE);
    int sN = 0, dN = 0, bt = -1;
    if (act) {
        if (e < Ep) { sN = src[e]; dN = dst[e]; bt = bond[e]; }
        else        { sN = dst[e - Ep]; dN = src[e - Ep]; bt = bond[e - Ep]; }
        const int p = atomicAdd(&rowFill[sN], 1);
        if (p < PAD) {
            edge_col[sN * PAD + p] = dN;
            edge_eid[sN * PAD + p] = e;
            padPos[e] = sN * PAD + p;
        } else padPos[e] = -1;
    }
    int myrank = 0;
#pragma unroll
    for (int t = 0; t < NB; ++t) {
        const unsigned long long m = __ballot(bt == t);
        if (lane == 0) wcnt[wave][t] = (int)__popcll(m);
        if (bt == t) myrank = (int)__popcll(m & ((1ull << lane) - 1ull));
    }
    __syncthreads();
    if (tid < NB) {
        int sum = 0;
#pragma unroll
        for (int w = 0; w < 4; ++w) { wbase[w][tid] = sum; sum += wcnt[w][tid]; }
    }
    __syncthreads();
    if (act) bond_edges[base_lds[bt] + wbase[wave][bt] + myrank] = e;

    // block 0: exact tile list (bondOff written by this block before the earlier barrier)
    if (vb == 0) {
        if (tid == 0) {
            tpre[0] = 0;
            for (int b = 0; b < NB; ++b) {
                const int cntb = bondOff[b + 1] - bondOff[b];
                tpre[b + 1] = tpre[b] + ((cntb + 63) >> 6);
            }
            ntiles[0] = tpre[NB];
        }
        __syncthreads();
        for (int i = tid; i < tpre[NB]; i += 256) {
            int b = 0;
            while (i >= tpre[b + 1]) ++b;
            tileBt[i] = b;
            tileT0[i] = (i - tpre[b]) << 6;
        }
    }
}

// ---- MFMA grouped edge MLP over exact tile list (1-D grid, no empty dispatches) ----
__global__ __launch_bounds__(256) void mlp_kernel(
    const unsigned short* __restrict__ Qbf, const unsigned short* __restrict__ Kbf,
    const int* __restrict__ src, const int* __restrict__ dst, int Ep,
    const int* __restrict__ bondOff, const int* __restrict__ bond_edges,
    const int* __restrict__ padPos,
    const int* __restrict__ tileBt, const int* __restrict__ tileT0,
    const int* __restrict__ ntiles,
    const unsigned short* __restrict__ W0p, const unsigned short* __restrict__ W1p,
    const float* __restrict__ b0, const float* __restrict__ b1,
    const float* __restrict__ W2, const float* __restrict__ b2,
    float* __restrict__ S)
{
    const int vt = blockIdx.x;
    if (vt >= ntiles[0]) return;
    const int bt = tileBt[vt];
    const int t0 = tileT0[vt];
    const int base = bondOff[bt];
    const int cnt  = bondOff[bt + 1] - base;
    const int ne = min(TILE, cnt - t0);

    // union: xs = buf[0:16K) during gather+layer0; h0(wave w) = buf[w*8K : w*8K+8K) after
    __shared__ __align__(16) unsigned char buf[32768];
    __shared__ int eids[TILE];

    const int tid = threadIdx.x;
    if (tid < TILE) eids[tid] = (tid < ne) ? bond_edges[base + t0 + tid] : 0;
    __syncthreads();

    // gather x = [Q[s] | K[d]] bf16 into swizzled xs
    for (int i = tid; i < 1024; i += 256) {
        const int el = i >> 4, u = i & 15;
        uint4 v = make_uint4(0, 0, 0, 0);
        if (el < ne) {
            const int e = eids[el];
            int s, d;
            if (e < Ep) { s = src[e]; d = dst[e]; }
            else        { s = dst[e - Ep]; d = src[e - Ep]; }
            v = (u < 8) ? ((const uint4*)(Qbf + s * 64))[u]
                        : ((const uint4*)(Kbf + d * 64))[u - 8];
        }
        const int b = (el << 8) + (u << 4);
        *(uint4*)(buf + (b ^ ((el & 7) << 4))) = v;
    }

    const int lane = tid & 63;
    const int h = tid >> 6;
    const int bh = bt * H + h;
    const int lg = lane >> 4;
    const int lr = lane & 15;

    // prefetch the epilogue's padPos (independent of LDS) so its latency hides under layer 0
    const int e_w = ((lr >> 2) << 4) + (lg << 2) + (lr & 3);
    const int pp = (e_w < ne) ? padPos[eids[e_w]] : -1;
    __syncthreads();

    // ---- layer 0: H0 = relu(X @ W0 + b0), K=128 ----
    f32x4 acc[4][4];
    const float* bb0 = b0 + bh * 64;
#pragma unroll
    for (int nt = 0; nt < 4; ++nt) {
        const float bv = bb0[(nt << 4) + lr];
#pragma unroll
        for (int mt = 0; mt < 4; ++mt) acc[mt][nt] = (f32x4){bv, bv, bv, bv};
    }
    const short8* W0f = (const short8*)W0p + (size_t)bh * 1024;
#pragma unroll
    for (int ks = 0; ks < 4; ++ks) {
        short8 a[4];
        const int koff = (ks << 6) + (lg << 4);
#pragma unroll
        for (int mt = 0; mt < 4; ++mt) {
            const int row = (mt << 4) + lr;
            const int b = (row << 8) + koff;
            a[mt] = *(const short8*)(buf + (b ^ ((row & 7) << 4)));
        }
        short8 bfr[4];
#pragma unroll
        for (int nt = 0; nt < 4; ++nt) bfr[nt] = W0f[(((ks << 2) + nt) << 6) + lane];
#pragma unroll
        for (int mt = 0; mt < 4; ++mt)
#pragma unroll
            for (int nt = 0; nt < 4; ++nt)
                acc[mt][nt] = __builtin_amdgcn_mfma_f32_16x16x32_bf16(a[mt], bfr[nt], acc[mt][nt], 0, 0, 0);
    }
    // all waves have consumed xs; safe to overlay H0 onto it
    __syncthreads();
    unsigned char* h0 = buf + h * 8192;
#pragma unroll
    for (int mt = 0; mt < 4; ++mt)
#pragma unroll
        for (int nt = 0; nt < 4; ++nt)
#pragma unroll
            for (int r = 0; r < 4; ++r) {
                const int row = (mt << 4) + (lg << 2) + r;
                const int col = (nt << 4) + lr;
                const int b = (row << 7) + (col << 1);
                *(unsigned short*)(h0 + (b ^ ((row & 7) << 4))) = f2bf(fmaxf(acc[mt][nt][r], 0.f));
            }

    // ---- layer 1: H1 = relu(H0 @ W1 + b1), K=64 ----
    f32x4 acc1[4][4];
    const float* bb1 = b1 + bh * 64;
#pragma unroll
    for (int nt = 0; nt < 4; ++nt) {
        const float bv = bb1[(nt << 4) + lr];
#pragma unroll
        for (int mt = 0; mt < 4; ++mt) acc1[mt][nt] = (f32x4){bv, bv, bv, bv};
    }
    const short8* W1f = (const short8*)W1p + (size_t)bh * 512;
#pragma unroll
    for (int ks = 0; ks < 2; ++ks) {
        short8 a[4];
        const int koff = (ks << 6) + (lg << 4);
#pragma unroll
        for (int mt = 0; mt < 4; ++mt) {
            const int row = (mt << 4) + lr;
            const int b = (row << 7) + koff;
            a[mt] = *(const short8*)(h0 + (b ^ ((row & 7) << 4)));
        }
        short8 bfr[4];
#pragma unroll
        for (int nt = 0; nt < 4; ++nt) bfr[nt] = W1f[(((ks << 2) + nt) << 6) + lane];
#pragma unroll
        for (int mt = 0; mt < 4; ++mt)
#pragma unroll
            for (int nt = 0; nt < 4; ++nt)
                acc1[mt][nt] = __builtin_amdgcn_mfma_f32_16x16x32_bf16(a[mt], bfr[nt], acc1[mt][nt], 0, 0, 0);
    }

    // ---- layer 2 + leaky relu ----
    const float* w2 = W2 + bh * 64;
    float w2v[4];
#pragma unroll
    for (int nt = 0; nt < 4; ++nt) w2v[nt] = w2[(nt << 4) + lr];
    float p[4][4];
#pragma unroll
    for (int mt = 0; mt < 4; ++mt)
#pragma unroll
        for (int r = 0; r < 4; ++r) {
            float s = 0.f;
#pragma unroll
            for (int nt = 0; nt < 4; ++nt) s += fmaxf(acc1[mt][nt][r], 0.f) * w2v[nt];
            p[mt][r] = s;
        }
#pragma unroll
    for (int off = 1; off <= 8; off <<= 1)
#pragma unroll
        for (int mt = 0; mt < 4; ++mt)
#pragma unroll
            for (int r = 0; r < 4; ++r) p[mt][r] += __shfl_xor(p[mt][r], off, 64);
    float sc = p[lr >> 2][lr & 3] + b2[bh];
    sc = sc > 0.f ? sc : NEG_SLOPE * sc;
    if (e_w < ne && pp >= 0) S[(size_t)pp * H + h] = sc;
}

// ---- agg: padded rows; softmax per head-wave; PV split across waves by edge; fused projection ----
__global__ __launch_bounds__(256) void agg_kernel(
    const float* __restrict__ V, const float* __restrict__ S,
    const int* __restrict__ rowFill,
    const int* __restrict__ edge_col, const int* __restrict__ edge_eid,
    const float* __restrict__ Pw, const float* __restrict__ Pb, float* __restrict__ out)
{
    const int row = blockIdx.x;
    const int tid = threadIdx.x;
    const int lane = tid & 63;
    const int wv = tid >> 6;
    const int beg = row * PAD;
    int deg = rowFill[row];
    if (deg > PAD) deg = PAD;

    __shared__ int tcol[PAD], teid[PAD], scol[PAD], spos[PAD], win[PAD];
    __shared__ float wgt[4][PAD];
    __shared__ float sdn[4];
    __shared__ float partv[4][4][64];
    __shared__ float rr[256];
    __shared__ float part2[4][64];

    for (int a = tid; a < deg; a += 256) { tcol[a] = edge_col[beg + a]; teid[a] = edge_eid[beg + a]; }
    __syncthreads();
    for (int a = tid; a < deg; a += 256) {
        const int e = teid[a];
        int r = 0;
        for (int b = 0; b < deg; ++b) r += (teid[b] < e);
        scol[r] = tcol[a];
        spos[r] = a;
    }
    __syncthreads();
    for (int a = tid; a < deg; a += 256) {
        const int c = scol[a];
        int wn = 1;
        for (int b = a + 1; b < deg; ++b) if (scol[b] == c) { wn = 0; break; }
        win[a] = wn;
    }
    __syncthreads();

    // softmax: wave wv handles head wv
    float m = -1e30f;
    for (int a = lane; a < deg; a += 64)
        if (win[a]) m = fmaxf(m, S[(size_t)(beg + spos[a]) * H + wv]);
#pragma unroll
    for (int off = 32; off; off >>= 1) m = fmaxf(m, __shfl_xor(m, off, 64));

    float dn = 0.f;
    for (int a = lane; a < deg; a += 64) {
        const float wvv = win[a] ? __expf(S[(size_t)(beg + spos[a]) * H + wv] - m) : 0.f;
        wgt[wv][a] = wvv;
        dn += wvv;
    }
#pragma unroll
    for (int off = 32; off; off >>= 1) dn += __shfl_xor(dn, off, 64);
    if (lane == 0) sdn[wv] = dn;
    __syncthreads();

    // PV: wave wv covers edges a = wv, wv+4, ...; each V row loaded once, used by all 4 heads
    float pv0 = 0.f, pv1 = 0.f, pv2 = 0.f, pv3 = 0.f;
    for (int a = wv; a < deg; a += 4) {
        const float vr = V[(size_t)scol[a] * D + lane];
        pv0 += wgt[0][a] * vr;
        pv1 += wgt[1][a] * vr;
        pv2 += wgt[2][a] * vr;
        pv3 += wgt[3][a] * vr;
    }
    partv[wv][0][lane] = pv0;
    partv[wv][1][lane] = pv1;
    partv[wv][2][lane] = pv2;
    partv[wv][3][lane] = pv3;
    __syncthreads();

    // reduce partials: wave wv owns head wv
    rr[wv * 64 + lane] = (partv[0][wv][lane] + partv[1][wv][lane]
                        + partv[2][wv][lane] + partv[3][wv][lane]) / sdn[wv];
    __syncthreads();

    // fused projection
    {
        float sps = 0.f;
#pragma unroll 8
        for (int k = 0; k < 64; ++k) sps += rr[wv * 64 + k] * Pw[(wv * 64 + k) * D + lane];
        part2[wv][lane] = sps;
    }
    __syncthreads();
    if (tid < 64)
        out[(size_t)row * D + tid] = part2[0][tid] + part2[1][tid] + part2[2][tid] + part2[3][tid] + Pb[tid];
}

extern "C" void kernel_launch(void* const* d_in, const int* in_sizes, int n_in,
                              void* d_out, int out_size, void* d_ws, size_t ws_size,
                              hipStream_t stream)
{
    const float* emb = (const float*)d_in[0];
    const float* Qw  = (const float*)d_in[1];
    const float* Qb  = (const float*)d_in[2];
    const float* Kw  = (const float*)d_in[3];
    const float* Kb  = (const float*)d_in[4];
    const float* Vw  = (const float*)d_in[5];
    const float* Vb  = (const float*)d_in[6];
    const float* W0  = (const float*)d_in[7];
    const float* b0  = (const float*)d_in[8];
    const float* W1  = (const float*)d_in[9];
    const float* b1  = (const float*)d_in[10];
    const float* W2  = (const float*)d_in[11];
    const float* b2  = (const float*)d_in[12];
    const float* Pw  = (const float*)d_in[13];
    const float* Pb  = (const float*)d_in[14];
    const int* src   = (const int*)d_in[15];
    const int* dst   = (const int*)d_in[16];
    const int* bond  = (const int*)d_in[17];

    const int N  = in_sizes[0] / D;
    const int Ep = in_sizes[15];
    const int TE = 2 * Ep;
    const int nblk = (TE + 255) / 256;
    const int nq8 = (N + 7) / 8;
    const int nhist = (nblk + 3) / 4;
    const int maxTiles = (TE + 63) / 64 + NB;

    char* w = (char*)d_ws;
    auto alloc = [&](size_t bytes) -> void* {
        void* p = (void*)w;
        w += ((bytes + 255) / 256) * 256;
        return p;
    };
    unsigned short* Qbf = (unsigned short*)alloc((size_t)N * D * 2);
    unsigned short* Kbf = (unsigned short*)alloc((size_t)N * D * 2);
    float* V        = (float*)alloc((size_t)N * D * 4);
    unsigned short* W0p = (unsigned short*)alloc((size_t)131072 * 2);
    unsigned short* W1p = (unsigned short*)alloc((size_t)65536 * 2);
    float* S        = (float*)alloc((size_t)N * PAD * H * 4);
    int* edge_col   = (int*)alloc((size_t)N * PAD * 4);
    int* edge_eid   = (int*)alloc((size_t)N * PAD * 4);
    int* bond_edges = (int*)alloc((size_t)TE * 4);
    int* padPos     = (int*)alloc((size_t)TE * 4);
    int* blockBondCnt = (int*)alloc((size_t)NB * nblk * 4);
    int* bondOff    = (int*)alloc((size_t)(NB + 1) * 4);
    int* rowFill    = (int*)alloc((size_t)N * 4);
    int* tileBt     = (int*)alloc((size_t)maxTiles * 4);
    int* tileT0     = (int*)alloc((size_t)maxTiles * 4);
    int* ntiles     = (int*)alloc(256);
    if ((size_t)(w - (char*)d_ws) > ws_size) return;

    prep_kernel<<<nq8 + 128 + nhist, 256, 0, stream>>>(
        emb, Qw, Qb, Kw, Kb, Vw, Vb, Qbf, Kbf, V, W0, W1, W0p, W1p,
        bond, Ep, TE, rowFill, blockBondCnt, nblk, N, nq8);
    scatter_kernel<<<nblk, 256, 0, stream>>>(
        src, dst, bond, Ep, TE, nblk, blockBondCnt, rowFill,
        edge_col, edge_eid, padPos, bond_edges, bondOff, tileBt, tileT0, ntiles);
    mlp_kernel<<<maxTiles, 256, 0, stream>>>(
        Qbf, Kbf, src, dst, Ep, bondOff, bond_edges, padPos, tileBt, tileT0, ntiles,
        W0p, W1p, b0, b1, W2, b2, S);
    agg_kernel<<<N, 256, 0, stream>>>(
        V, S, rowFill, edge_col, edge_eid, Pw, Pb, (float*)d_out);
}